// Round 26
// baseline (175.275 us; speedup 1.0000x reference)
//
#include <hip/hip_runtime.h>
#include <stdint.h>

#define FEAT_STRIDE_I 16
#define A_NUM 9
#define HH 128
#define WW 128
#define NPIX (HH * WW)            // 16384
#define N_ANCH (NPIX * A_NUM)     // 147456
#define B_NUM 8
#define PRE_NMS 6000
#define POST_NMS 300
#define NMS_THRESH_F 0.7f
#define MIN_SIZE_F 16.0f
#define NEG_INF_F -1e30f

#define NBS 16384                  // 14-bit bins (key>>18)
#define SWS(i) ((i) + ((i) >> 5))  // LDS swizzle
// cache-line spread for the mutable bin counters (round 24: -45us on scatter)
#define SWB(bin) ((((bin) & 1023) << 4) | ((bin) >> 10))
#define SEGL 8192                  // candidate segment cap (cnt ~6700 max)
#define QKEYS (N_ANCH / 4)         // 36864 keys per hist part

#define RT_TILES 94                // ceil(6000/64)
#define GT_TILES 600               // sum_R ceil((94-R)/8): 8-column groups
#define BQWORDS (RT_TILES * RT_TILES * 64)   // 565,504 qwords per batch

// truncated-IoU split: phase A computes row-tiles R < R_SPLIT (rows 0..1023);
// the tail (R >= R_SPLIT) is skipped per batch when the scan already kept 300.
#define R_SPLIT 16
#define ROWS_SPLIT (R_SPLIT * 64)  // 1024
#define G_HEAD 180                 // sum_{R=0..15} (101-R)>>3
#define G_TAIL (GT_TILES - G_HEAD) // 420
#define STATE_STRIDE 2048          // per-batch scan state (kept,done,supp,klist)
#define TMQ (ROWS_SPLIT * RT_TILES)            // 96,256 qwords per batch

// ---- workspace layout (bytes) ----
// KEYS and PHIST are dead by the time k_transpose runs; the row-major head
// mask (TMASK, 6,160,384 B) overlays them — no extra ws needed.
#define OFF_KEYS    0u             // 8*147456*4 = 4,718,592
#define OFF_PHIST   4718592u       // 8*4*16384*4 = 2,097,152 -> ends 6,815,744
#define OFF_TMASK   0u             // 8*96256*8 = 6,160,384 (overlay, late-use)
#define OFF_BOXES   6815744u       // 8*6000*4*4 = 768,000
#define OFF_BBRO    7583744u       // 8*16384*4 = 524,288 (read-only binbase)
#define OFF_BBMUT   8108032u       // 524,288 (scatter slot counters, swizzled)
#define OFF_CNT     8632320u       // thresh[8] + cnt[8] (512 B)
#define OFF_SEG     8632832u       // 8*8192*8 = 524,288
#define OFF_RIDX    9157120u       // 8*6000*4 = 192,000
#define OFF_STATE   9349120u       // 8*2048 = 16,384
#define OFF_MASK    9365504u       // 36,192,256 -> end 45,557,760
#define MASK_BYTES ((size_t)B_NUM * BQWORDS * 8)

__device__ __forceinline__ unsigned sortable_f32(float f) {
    unsigned u = __float_as_uint(f);
    return (u & 0x80000000u) ? ~u : (u | 0x80000000u);
}

// Decode one anchor's box exactly in the reference's op order.
__device__ __forceinline__ void decode_box(
    int b, int idx,
    const float* __restrict__ deltas, const float* __restrict__ im_info,
    const float* __restrict__ anchors,
    float& x1, float& y1, float& x2, float& y2, bool& valid)
{
    int a   = idx % A_NUM;
    int pix = idx / A_NUM;
    int w   = pix & (WW - 1);
    int h   = pix >> 7;

    float a0 = anchors[a * 4 + 0];
    float a1 = anchors[a * 4 + 1];
    float a2 = anchors[a * 4 + 2];
    float a3 = anchors[a * 4 + 3];

    float aw = __fadd_rn(__fsub_rn(a2, a0), 1.0f);
    float ah = __fadd_rn(__fsub_rn(a3, a1), 1.0f);
    float sx = (float)(w * FEAT_STRIDE_I);
    float sy = (float)(h * FEAT_STRIDE_I);
    float acx = __fadd_rn(__fadd_rn(sx, a0), __fmul_rn(0.5f, aw));
    float acy = __fadd_rn(__fadd_rn(sy, a1), __fmul_rn(0.5f, ah));

    size_t base = ((size_t)b * 36 + 4 * a) * NPIX + pix;
    float dx = deltas[base];
    float dy = deltas[base + NPIX];
    float dw = deltas[base + 2 * (size_t)NPIX];
    float dh = deltas[base + 3 * (size_t)NPIX];

    float pcx = __fadd_rn(__fmul_rn(dx, aw), acx);
    float pcy = __fadd_rn(__fmul_rn(dy, ah), acy);
    float pw  = __fmul_rn(expf(dw), aw);
    float ph  = __fmul_rn(expf(dh), ah);

    float hx = __fmul_rn(0.5f, pw);
    float hy = __fmul_rn(0.5f, ph);
    x1 = __fsub_rn(pcx, hx);
    y1 = __fsub_rn(pcy, hy);
    x2 = __fadd_rn(pcx, hx);
    y2 = __fadd_rn(pcy, hy);

    float im_h = im_info[b * 3 + 0];
    float im_w = im_info[b * 3 + 1];
    float sc   = im_info[b * 3 + 2];
    float wmax = __fsub_rn(im_w, 1.0f);
    float hmax = __fsub_rn(im_h, 1.0f);

    x1 = fminf(fmaxf(x1, 0.0f), wmax);
    y1 = fminf(fmaxf(y1, 0.0f), hmax);
    x2 = fminf(fmaxf(x2, 0.0f), wmax);
    y2 = fminf(fmaxf(y2, 0.0f), hmax);

    float min_sz = __fmul_rn(MIN_SIZE_F, sc);
    valid = (__fadd_rn(__fsub_rn(x2, x1), 1.0f) >= min_sz) &&
            (__fadd_rn(__fsub_rn(y2, y1), 1.0f) >= min_sz);
}

// K1: decode + masked score -> sortable key. Pure streaming, no atomics.
__global__ void k_decode(
    const float* __restrict__ scores, const float* __restrict__ deltas,
    const float* __restrict__ im_info, const float* __restrict__ anchors,
    unsigned* __restrict__ keys)
{
    int gt = blockIdx.x * blockDim.x + threadIdx.x;
    if (gt >= B_NUM * N_ANCH) return;
    int pix  = gt & (NPIX - 1);
    int rest = gt >> 14;
    int a = rest % A_NUM;
    int b = rest / A_NUM;
    int idx = pix * A_NUM + a;

    float x1, y1, x2, y2; bool valid;
    decode_box(b, idx, deltas, im_info, anchors, x1, y1, x2, y2, valid);

    float s = scores[((size_t)b * 18 + 9 + a) * NPIX + pix];
    if (!valid) s = NEG_INF_F;
    keys[gt] = sortable_f32(s);
}

// K2: partial histograms — 4 blocks per batch, each hists one quarter of
// the keys in a private LDS 16384-bin histogram (staged uint4 loads).
__global__ __launch_bounds__(1024) void k_hist_part(
    const unsigned* __restrict__ keys, unsigned* __restrict__ phist)
{
    __shared__ unsigned h[SWS(NBS - 1) + 2];   // 16896 words = 67.6 KB
    int b = blockIdx.x >> 2;
    int p = blockIdx.x & 3;
    int t = threadIdx.x;

    for (int i = t; i < SWS(NBS - 1) + 2; i += 1024) h[i] = 0u;
    __syncthreads();

    const uint4* kb4 = (const uint4*)(keys + (size_t)b * N_ANCH + p * QKEYS);
    uint4 v[9];
    #pragma unroll
    for (int k = 0; k < 9; ++k) v[k] = kb4[t + 1024 * k];
    #pragma unroll
    for (int k = 0; k < 9; ++k) {
        atomicAdd(&h[SWS(v[k].x >> 18)], 1u);
        atomicAdd(&h[SWS(v[k].y >> 18)], 1u);
        atomicAdd(&h[SWS(v[k].z >> 18)], 1u);
        atomicAdd(&h[SWS(v[k].w >> 18)], 1u);
    }
    __syncthreads();

    unsigned* ph = phist + (size_t)blockIdx.x * NBS;
    for (int i = t; i < NBS; i += 1024) ph[i] = h[SWS(i)];
}

// K3: per batch — sum 4 partials, suffix-scan 16384 bins, find threshold T.
// bbro linear (read by k_rank); bbmut written SWB-swizzled (scatter atomics).
__global__ __launch_bounds__(1024) void k_thresh2(
    const unsigned* __restrict__ phist, unsigned* __restrict__ bbro,
    unsigned* __restrict__ bbmut, unsigned* __restrict__ thresh,
    unsigned* __restrict__ cnt)
{
    __shared__ unsigned h[SWS(NBS - 1) + 2];
    __shared__ unsigned csum[1024];
    __shared__ unsigned sT;

    int b = blockIdx.x;
    int t = threadIdx.x;
    if (t == 0) sT = 0;

    const unsigned* ph = phist + (size_t)b * 4 * NBS;
    for (int i = t; i < NBS; i += 1024) {
        unsigned s0 = ph[i];
        unsigned s1 = ph[NBS + i];
        unsigned s2 = ph[2 * NBS + i];
        unsigned s3 = ph[3 * NBS + i];
        h[SWS(i)] = s0 + s1 + s2 + s3;
    }
    __syncthreads();

    int base = t * 16;
    unsigned s = 0;
    for (int u = 0; u < 16; ++u) s += h[SWS(base + u)];
    csum[t] = s;
    __syncthreads();
    for (int off = 1; off < 1024; off <<= 1) {
        unsigned v = (t + off < 1024) ? csum[t + off] : 0u;
        __syncthreads();
        csum[t] += v;
        __syncthreads();
    }
    unsigned before = csum[t] - s;

    unsigned acc = before;
    for (int bin = base + 15; bin >= base; --bin) {
        unsigned hh = h[SWS(bin)];
        if (acc + hh >= PRE_NMS) { atomicMax(&sT, (unsigned)bin); break; }
        acc += hh;
    }
    __syncthreads();
    unsigned T = sT;

    acc = before;
    for (int bin = base + 15; bin >= base; --bin) {
        unsigned hh = h[SWS(bin)];
        if ((unsigned)bin == T) cnt[b] = acc + hh;
        h[SWS(bin)] = acc;
        acc += hh;
    }
    if (t == 0) thresh[b] = T;
    __syncthreads();

    unsigned* r = bbro + (size_t)b * NBS;
    unsigned* m = bbmut + (size_t)b * NBS;
    for (int i = t; i < NBS; i += 1024) {
        unsigned v = h[SWS(i)];
        r[i] = v;
        m[SWB(i)] = v;
    }
}

// K4: bin-segmented scatter — slot allocated by atomicAdd on the SWIZZLED
// mutable binbase copy.
__global__ void k_scatter(
    const unsigned* __restrict__ keys, const unsigned* __restrict__ thresh,
    unsigned* __restrict__ bbmut, unsigned long long* __restrict__ seg)
{
    int gt = blockIdx.x * blockDim.x + threadIdx.x;
    int pix  = gt & (NPIX - 1);
    int rest = gt >> 14;
    int a = rest % A_NUM;
    int b = rest / A_NUM;

    unsigned key = keys[gt];
    unsigned bin = key >> 18;
    if (bin >= thresh[b]) {
        unsigned pos = atomicAdd(&bbmut[(size_t)b * NBS + SWB(bin)], 1u);
        if (pos < SEGL) {
            unsigned idx = (unsigned)(pix * A_NUM + a);
            seg[(size_t)b * SEGL + pos] =
                ((unsigned long long)key << 32) | (unsigned long long)(0xFFFFFFFFu - idx);
        }
    }
}

// K5a: many-block counting rank (32 blocks x 256 thr per batch, all CUs).
__global__ __launch_bounds__(256) void k_rank(
    const unsigned long long* __restrict__ seg, const unsigned* __restrict__ cnt,
    const unsigned* __restrict__ bbro, unsigned* __restrict__ ridx)
{
    int b = blockIdx.x >> 5;
    int p = ((blockIdx.x & 31) << 8) + threadIdx.x;
    unsigned n = cnt[b];
    if (n > SEGL) n = SEGL;
    if (p >= (int)n) return;

    const unsigned long long* S = seg + (size_t)b * SEGL;
    unsigned long long key = S[p];
    unsigned bin = (unsigned)(key >> 50);
    const unsigned* bb = bbro + (size_t)b * NBS;
    unsigned base = bb[bin];
    unsigned end = (bin > 0) ? bb[bin - 1] : n;
    if (end > n) end = n;

    unsigned rank = base;
    unsigned q = base;
    for (; q + 8 <= end; q += 8) {
        unsigned long long v0 = S[q + 0], v1 = S[q + 1];
        unsigned long long v2 = S[q + 2], v3 = S[q + 3];
        unsigned long long v4 = S[q + 4], v5 = S[q + 5];
        unsigned long long v6 = S[q + 6], v7 = S[q + 7];
        rank += (unsigned)(v0 > key) + (unsigned)(v1 > key)
              + (unsigned)(v2 > key) + (unsigned)(v3 > key)
              + (unsigned)(v4 > key) + (unsigned)(v5 > key)
              + (unsigned)(v6 > key) + (unsigned)(v7 > key);
    }
    for (; q < end; ++q) rank += (unsigned)(S[q] > key);

    if (rank < PRE_NMS)
        ridx[(size_t)b * PRE_NMS + rank] = 0xFFFFFFFFu - (unsigned)(key & 0xFFFFFFFFull);
}

// K5b: decode one box per output rank across all CUs.
__global__ void k_decode2(
    const unsigned* __restrict__ ridx,
    const float* __restrict__ deltas, const float* __restrict__ im_info,
    const float* __restrict__ anchors, float* __restrict__ boxes)
{
    int gt = blockIdx.x * blockDim.x + threadIdx.x;
    if (gt >= B_NUM * PRE_NMS) return;
    int b = gt / PRE_NMS;
    int idx = (int)ridx[gt];
    float x1, y1, x2, y2; bool v;
    decode_box(b, idx, deltas, im_info, anchors, x1, y1, x2, y2, v);
    *(float4*)(boxes + (size_t)gt * 4) = make_float4(x1, y1, x2, y2);
}

// One row of a 64x64 suppression block (exact ref op order; div only in the
// proven +-6e-7*uni band — validated absmax=0 since round 6).
__device__ __forceinline__ unsigned long long iou_row(
    float4 bi, float ia, float jx1, float jy1, float jx2, float jy2, float ja)
{
    float xx1 = fmaxf(bi.x, jx1);
    float yy1 = fmaxf(bi.y, jy1);
    float xx2 = fminf(bi.z, jx2);
    float yy2 = fminf(bi.w, jy2);
    float iw = fmaxf(0.0f, __fadd_rn(__fsub_rn(xx2, xx1), 1.0f));
    float ih = fmaxf(0.0f, __fadd_rn(__fsub_rn(yy2, yy1), 1.0f));
    float inter = __fmul_rn(iw, ih);
    float uni = __fsub_rn(__fadd_rn(ia, ja), inter);
    float diff = __fsub_rn(inter, __fmul_rn(NMS_THRESH_F, uni));
    unsigned long long sup = __ballot(diff > 0.0f);
    unsigned long long band = __ballot(fabsf(diff) <= __fmul_rn(6e-7f, uni));
    if (band) {
        unsigned long long supd = __ballot(__fdiv_rn(inter, uni) > NMS_THRESH_F);
        sup = (sup & ~band) | (supd & band);
    }
    return sup;
}

// K6: IoU suppression bitmask for row-tiles R in [Rstart, ...), ngroups
// 8-column groups per batch. statep!=null: skip batch if its scan already
// finished (done flag). Layout mask[b][R][C][64].
__global__ __launch_bounds__(256) void k_iou_mask(
    const float* __restrict__ boxes, unsigned long long* __restrict__ mask,
    int Rstart, int ngroups, const char* __restrict__ statep)
{
    int bid = blockIdx.x;
    int b = bid / ngroups;
    int g = bid - b * ngroups;
    if (statep && ((const int*)(statep + (size_t)b * STATE_STRIDE))[1]) return;

    int R = Rstart;
    while (g >= ((RT_TILES - R + 7) >> 3)) { g -= (RT_TILES - R + 7) >> 3; ++R; }

    int wave = threadIdx.x >> 6;
    int lane = threadIdx.x & 63;
    const float* Bb = boxes + (size_t)b * PRE_NMS * 4;

    __shared__ float4 rb4[64];
    __shared__ float rba[64];
    if (threadIdx.x < 64) {
        int il = R * 64 + threadIdx.x;
        float4 rv = make_float4(0.f, 0.f, -1.f, -1.f);
        if (il < PRE_NMS) rv = *(const float4*)(Bb + 4 * (size_t)il);
        rb4[threadIdx.x] = rv;
        rba[threadIdx.x] = __fmul_rn(__fadd_rn(__fsub_rn(rv.z, rv.x), 1.0f),
                                     __fadd_rn(__fsub_rn(rv.w, rv.y), 1.0f));
    }
    __syncthreads();

    int C1 = R + g * 8 + wave * 2;
    int C2 = C1 + 1;
    if (C1 >= RT_TILES) return;   // tail waves idle (no barriers below)

    float j1x1 = 0.f, j1y1 = 0.f, j1x2 = -1.f, j1y2 = -1.f;
    float j2x1 = 0.f, j2y1 = 0.f, j2x2 = -1.f, j2y2 = -1.f;
    int j1 = C1 * 64 + lane;
    int j2 = C2 * 64 + lane;
    if (j1 < PRE_NMS) {
        float4 v = *(const float4*)(Bb + 4 * (size_t)j1);
        j1x1 = v.x; j1y1 = v.y; j1x2 = v.z; j1y2 = v.w;
    }
    if (C2 < RT_TILES && j2 < PRE_NMS) {
        float4 v = *(const float4*)(Bb + 4 * (size_t)j2);
        j2x1 = v.x; j2y1 = v.y; j2x2 = v.z; j2y2 = v.w;
    }
    float j1a = __fmul_rn(__fadd_rn(__fsub_rn(j1x2, j1x1), 1.0f),
                          __fadd_rn(__fsub_rn(j1y2, j1y1), 1.0f));
    float j2a = __fmul_rn(__fadd_rn(__fsub_rn(j2x2, j2x1), 1.0f),
                          __fadd_rn(__fsub_rn(j2y2, j2y1), 1.0f));

    unsigned long long w1 = 0ULL, w2 = 0ULL;
    if (C1 == R) {   // diagonal tile
        #pragma unroll 4
        for (int ri = 0; ri < 64; ++ri) {
            float4 bi = rb4[ri];
            float ia = rba[ri];
            unsigned long long s1 = iou_row(bi, ia, j1x1, j1y1, j1x2, j1y2, j1a)
                                    & (0xFFFFFFFFFFFFFFFEull << ri);
            unsigned long long s2 = iou_row(bi, ia, j2x1, j2y1, j2x2, j2y2, j2a);
            w1 = (lane == ri) ? s1 : w1;
            w2 = (lane == ri) ? s2 : w2;
        }
    } else {
        #pragma unroll 4
        for (int ri = 0; ri < 64; ++ri) {
            float4 bi = rb4[ri];
            float ia = rba[ri];
            unsigned long long s1 = iou_row(bi, ia, j1x1, j1y1, j1x2, j1y2, j1a);
            unsigned long long s2 = iou_row(bi, ia, j2x1, j2y1, j2x2, j2y2, j2a);
            w1 = (lane == ri) ? s1 : w1;
            w2 = (lane == ri) ? s2 : w2;
        }
    }

    unsigned long long* Mb = mask + (size_t)b * BQWORDS;
    Mb[(size_t)(R * RT_TILES + C1) * 64 + lane] = w1;
    if (C2 < RT_TILES)
        Mb[(size_t)(R * RT_TILES + C2) * 64 + lane] = w2;
}

// K6b: transpose head mask [R][C][64] -> row-major tmask[i][C] for rows
// < ROWS_SPLIT.
__global__ __launch_bounds__(1024) void k_transpose(
    const unsigned long long* __restrict__ mask,
    unsigned long long* __restrict__ tmask)
{
    __shared__ unsigned long long tile[64 * RT_TILES];   // 48,128 B
    int b = blockIdx.x >> 4;
    int R = blockIdx.x & 15;
    int t = threadIdx.x;
    const unsigned long long* Mb =
        mask + (size_t)b * BQWORDS + (size_t)R * RT_TILES * 64;
    for (int idx = t; idx < RT_TILES * 64; idx += 1024) {
        int C = idx >> 6, r = idx & 63;
        tile[r * RT_TILES + C] = Mb[(size_t)C * 64 + r];
    }
    __syncthreads();
    unsigned long long* Tb =
        tmask + (size_t)b * TMQ + (size_t)R * 64 * RT_TILES;
    for (int idx = t; idx < 64 * RT_TILES; idx += 1024)
        Tb[idx] = tile[idx];
}

// K7: greedy scan, resumable. One wave/batch. Suppression state in
// registers (lane l owns words l, 64+l).
// p1 (final_phase==0): TILE-RESOLVE scan, round-26: diagonals of all 16
// head tiles PREFETCHED up-front (static addresses, one round trip);
// per tile, only the KEPT rows (avg ~19, wave-uniform keptm) are gathered
// and OR'd — round-25 loaded all 64 rows in 8 batched round trips, which
// was the measured 56us (16 tiles x 8 L2 round trips). Extracting <=8 set
// bits at a time (first row duplicated as filler; double-OR harmless)
// keeps loads unconditional and pipelined: ~1 round trip per tile.
// p2 (final_phase==1): old per-row path on the strided mask layout.
__global__ __launch_bounds__(64) void k_nms_scan_part(
    const unsigned long long* __restrict__ mask,
    const unsigned long long* __restrict__ tmask,
    const float* __restrict__ boxes, float* __restrict__ out,
    char* __restrict__ statep, int row_begin, int row_end, int final_phase)
{
    const int b = blockIdx.x;
    const int l = threadIdx.x;
    char* st = statep + (size_t)b * STATE_STRIDE;
    int* s_meta = (int*)st;
    unsigned long long* s_supp = (unsigned long long*)(st + 16);
    int* s_klist = (int*)(st + 768);

    __shared__ int klist[POST_NMS];
    unsigned long long reg0, reg1;   // suppression words l and 64+l
    int kept, done;

    if (row_begin == 0) {
        reg0 = 0ULL; reg1 = 0ULL;
        kept = 0; done = 0;
    } else {
        kept = s_meta[0];
        done = s_meta[1];
        reg0 = s_supp[l];
        reg1 = (l < RT_TILES - 64) ? s_supp[64 + l] : 0ULL;
        for (int k = l; k < POST_NMS; k += 64) klist[k] = s_klist[k];
    }
    __syncthreads();

    const unsigned long long* __restrict__ M = mask + (size_t)b * BQWORDS;
    const unsigned long long* __restrict__ TM = tmask + (size_t)b * TMQ;

#define LOADROW(p0, p1, i) { \
        int _i = ((i) < PRE_NMS) ? (i) : (PRE_NMS - 1); \
        int _R = _i >> 6; \
        const unsigned long long* _r = M + (size_t)(_R * RT_TILES) * 64 + (_i & 63); \
        p0 = 0ULL; p1 = 0ULL; \
        if (l >= _R) p0 = _r[l * 64]; \
        if (l < RT_TILES - 64 && 64 + l >= _R) p1 = _r[(64 + l) * 64]; }

#define STEP(i, p0, p1) { \
        if (kept < POST_NMS) { \
            int _wi = (i) >> 6; \
            if (_wi != curwi) { \
                curw = (_wi < 64) ? __shfl(reg0, _wi) : __shfl(reg1, _wi - 64); \
                curwi = _wi; \
            } \
            if (!((curw >> ((i) & 63)) & 1ULL)) { \
                if (l == 0) klist[kept] = (i); \
                unsigned long long _d = (_wi < 64) ? __shfl(p0, _wi) \
                                                   : __shfl(p1, _wi - 64); \
                reg0 |= p0; \
                reg1 |= p1; \
                curw |= _d; \
                ++kept; \
            } \
        } }

    if (!done && kept < POST_NMS) {
        if (!final_phase) {
            // prefetch all 16 head-tile diagonal words (static addresses)
            unsigned long long diag[R_SPLIT];
            #pragma unroll
            for (int T = 0; T < R_SPLIT; ++T)
                diag[T] = TM[(size_t)(T * 64 + l) * RT_TILES + T];

            for (int T = 0; T < R_SPLIT && kept < POST_NMS; ++T) {
                int base = T << 6;
                unsigned long long sup_w = __shfl(reg0, T);   // T < 16 < 64
                unsigned long long alive = ~sup_w;
                unsigned long long d = diag[T];
                unsigned long long keptm = 0ULL;

                while (alive && kept < POST_NMS) {
                    int r = __ffsll(alive) - 1;
                    if (l == 0) klist[kept] = base + r;
                    ++kept;
                    keptm |= (1ULL << r);
                    unsigned long long dr = __shfl(d, r);
                    alive &= ~dr;
                    alive &= ~(1ULL << r);
                }

                // gather ONLY the kept rows (wave-uniform keptm), <=8 at a
                // time; filler = first row (double-OR harmless)
                unsigned long long km = keptm;
                while (km) {
                    int rfirst = __ffsll(km) - 1;
                    int rr[8];
                    #pragma unroll
                    for (int k = 0; k < 8; ++k) {
                        if (km) { rr[k] = __ffsll(km) - 1; km &= km - 1ULL; }
                        else rr[k] = rfirst;
                    }
                    unsigned long long w0[8], w1[8];
                    #pragma unroll
                    for (int k = 0; k < 8; ++k) {
                        const unsigned long long* _r =
                            TM + (size_t)(base + rr[k]) * RT_TILES;
                        w0[k] = _r[l];
                        w1[k] = (l < RT_TILES - 64) ? _r[64 + l] : 0ULL;
                    }
                    #pragma unroll
                    for (int k = 0; k < 8; ++k) { reg0 |= w0[k]; reg1 |= w1[k]; }
                }
            }
        } else {
            unsigned long long curw = 0; int curwi = -1;
            unsigned long long p[16][2];
            #pragma unroll
            for (int k = 0; k < 16; ++k) { LOADROW(p[k][0], p[k][1], row_begin + k) }
            for (int i = row_begin; i < row_end && kept < POST_NMS; i += 16) {
                #pragma unroll
                for (int k = 0; k < 16; ++k) {
                    STEP(i + k, p[k][0], p[k][1])
                    LOADROW(p[k][0], p[k][1], i + 16 + k)
                }
            }
        }
    }
    __syncthreads();

    if (!final_phase) {
        if (l == 0) { s_meta[0] = kept; s_meta[1] = (kept >= POST_NMS) ? 1 : 0; }
        s_supp[l] = reg0;
        if (l < RT_TILES - 64) s_supp[64 + l] = reg1;
        for (int k = l; k < POST_NMS; k += 64) s_klist[k] = klist[k];
    } else {
        for (int k = l; k < POST_NMS; k += 64) {
            size_t o = ((size_t)b * POST_NMS + k) * 5;
            float x1 = 0.f, y1 = 0.f, x2 = 0.f, y2 = 0.f;
            if (k < kept) {
                int idx = klist[k];
                const float4 v = *(const float4*)(boxes + ((size_t)b * PRE_NMS + idx) * 4);
                x1 = v.x; y1 = v.y; x2 = v.z; y2 = v.w;
            }
            out[o + 0] = (float)b;
            out[o + 1] = x1; out[o + 2] = y1; out[o + 3] = x2; out[o + 4] = y2;
        }
    }
#undef LOADROW
#undef STEP
}

// Fallback NMS (used only if ws_size is too small for the bitmask).
__global__ __launch_bounds__(1024) void k_nms_out(
    const float* __restrict__ boxes, float* __restrict__ out)
{
    __shared__ float bx1[PRE_NMS], by1[PRE_NMS], bx2[PRE_NMS], by2[PRE_NMS], bar[PRE_NMS];
    __shared__ unsigned rem[(PRE_NMS + 31) / 32];
    __shared__ int kept_idx[POST_NMS];

    int b = blockIdx.x;
    int t = threadIdx.x;

    for (int p = t; p < PRE_NMS; p += 1024) {
        size_t o = ((size_t)b * PRE_NMS + p) * 4;
        float x1 = boxes[o], y1 = boxes[o + 1], x2 = boxes[o + 2], y2 = boxes[o + 3];
        bx1[p] = x1; by1[p] = y1; bx2[p] = x2; by2[p] = y2;
        bar[p] = __fmul_rn(__fadd_rn(__fsub_rn(x2, x1), 1.0f),
                           __fadd_rn(__fsub_rn(y2, y1), 1.0f));
    }
    for (int p = t; p < (PRE_NMS + 31) / 32; p += 1024) rem[p] = 0u;
    __syncthreads();

    int kept = 0;
    for (int i = 0; i < PRE_NMS && kept < POST_NMS; ++i) {
        if (rem[i >> 5] & (1u << (i & 31))) continue;
        if (t == 0) kept_idx[kept] = i;
        float xi1 = bx1[i], yi1 = by1[i], xi2 = bx2[i], yi2 = by2[i], ai = bar[i];
        for (int j = i + 1 + t; j < PRE_NMS; j += 1024) {
            float xx1 = fmaxf(xi1, bx1[j]);
            float yy1 = fmaxf(yi1, by1[j]);
            float xx2 = fminf(xi2, bx2[j]);
            float yy2 = fminf(yi2, by2[j]);
            float iw = fmaxf(0.0f, __fadd_rn(__fsub_rn(xx2, xx1), 1.0f));
            float ih = fmaxf(0.0f, __fadd_rn(__fsub_rn(yy2, yy1), 1.0f));
            float inter = __fmul_rn(iw, ih);
            if (inter > 0.0f) {
                float uni = __fsub_rn(__fadd_rn(ai, bar[j]), inter);
                float iou = __fdiv_rn(inter, uni);
                if (iou > NMS_THRESH_F) atomicOr(&rem[j >> 5], 1u << (j & 31));
            }
        }
        ++kept;
        __syncthreads();
    }

    for (int k = t; k < POST_NMS; k += 1024) {
        size_t o = ((size_t)b * POST_NMS + k) * 5;
        out[o] = (float)b;
        if (k < kept) {
            int ii = kept_idx[k];
            out[o + 1] = bx1[ii]; out[o + 2] = by1[ii];
            out[o + 3] = bx2[ii]; out[o + 4] = by2[ii];
        } else {
            out[o + 1] = 0.0f; out[o + 2] = 0.0f; out[o + 3] = 0.0f; out[o + 4] = 0.0f;
        }
    }
}

extern "C" void kernel_launch(void* const* d_in, const int* in_sizes, int n_in,
                              void* d_out, int out_size, void* d_ws, size_t ws_size,
                              hipStream_t stream)
{
    const float* scores  = (const float*)d_in[0];
    const float* deltas  = (const float*)d_in[1];
    const float* im_info = (const float*)d_in[2];
    const float* anchors = (const float*)d_in[3];
    float* out = (float*)d_out;
    char* ws = (char*)d_ws;

    unsigned* keys             = (unsigned*)(ws + OFF_KEYS);
    unsigned* phist            = (unsigned*)(ws + OFF_PHIST);
    unsigned long long* tmask  = (unsigned long long*)(ws + OFF_TMASK);
    float* boxes               = (float*)(ws + OFF_BOXES);
    unsigned* bbro             = (unsigned*)(ws + OFF_BBRO);
    unsigned* bbmut            = (unsigned*)(ws + OFF_BBMUT);
    unsigned* thresh           = (unsigned*)(ws + OFF_CNT);
    unsigned* cnt              = thresh + 8;
    unsigned long long* seg    = (unsigned long long*)(ws + OFF_SEG);
    unsigned* ridx             = (unsigned*)(ws + OFF_RIDX);
    char* state                = (char*)(ws + OFF_STATE);
    unsigned long long* mask   = (unsigned long long*)(ws + OFF_MASK);

    int total = B_NUM * N_ANCH;
    int blk = 256;
    k_decode<<<(total + blk - 1) / blk, blk, 0, stream>>>(
        scores, deltas, im_info, anchors, keys);
    k_hist_part<<<B_NUM * 4, 1024, 0, stream>>>(keys, phist);
    k_thresh2<<<B_NUM, 1024, 0, stream>>>(phist, bbro, bbmut, thresh, cnt);
    k_scatter<<<(total + blk - 1) / blk, blk, 0, stream>>>(
        keys, thresh, bbmut, seg);
    k_rank<<<B_NUM * 32, 256, 0, stream>>>(seg, cnt, bbro, ridx);
    k_decode2<<<(B_NUM * PRE_NMS + blk - 1) / blk, blk, 0, stream>>>(
        ridx, deltas, im_info, anchors, boxes);

    if (ws_size >= (size_t)OFF_MASK + MASK_BYTES) {
        // phase A: rows 0..1023 only
        k_iou_mask<<<B_NUM * G_HEAD, 256, 0, stream>>>(
            boxes, mask, 0, G_HEAD, (const char*)0);
        // transpose head rows to row-major (overlays dead keys/phist)
        k_transpose<<<B_NUM * R_SPLIT, 1024, 0, stream>>>(mask, tmask);
        // scan p1: tile-resolve, kept-row-only gather
        k_nms_scan_part<<<B_NUM, 64, 0, stream>>>(
            mask, tmask, boxes, out, state, 0, ROWS_SPLIT, 0);
        // tail: rows >= 1024, skipped per batch when done
        k_iou_mask<<<B_NUM * G_TAIL, 256, 0, stream>>>(
            boxes, mask, R_SPLIT, G_TAIL, (const char*)state);
        // scan p2: finish (or just write output if already done)
        k_nms_scan_part<<<B_NUM, 64, 0, stream>>>(
            mask, tmask, boxes, out, state, ROWS_SPLIT, PRE_NMS, 1);
    } else {
        k_nms_out<<<B_NUM, 1024, 0, stream>>>(boxes, out);
    }
}

// Round 27
// 172.269 us; speedup vs baseline: 1.0174x; 1.0174x over previous
//
#include <hip/hip_runtime.h>
#include <stdint.h>

#define FEAT_STRIDE_I 16
#define A_NUM 9
#define HH 128
#define WW 128
#define NPIX (HH * WW)            // 16384
#define N_ANCH (NPIX * A_NUM)     // 147456
#define B_NUM 8
#define PRE_NMS 6000
#define POST_NMS 300
#define NMS_THRESH_F 0.7f
#define MIN_SIZE_F 16.0f
#define NEG_INF_F -1e30f

#define NBS 16384                  // 14-bit bins (key>>18)
#define SWS(i) ((i) + ((i) >> 5))  // LDS swizzle
// cache-line spread for the mutable bin counters (round 24: -45us on scatter)
#define SWB(bin) ((((bin) & 1023) << 4) | ((bin) >> 10))
#define SEGL 8192                  // candidate segment cap (cnt ~6700 max)
#define QKEYS (N_ANCH / 4)         // 36864 keys per hist part

#define RT_TILES 94                // ceil(6000/64)
#define GT_TILES 600               // sum_R ceil((94-R)/8): 8-column groups
#define BQWORDS (RT_TILES * RT_TILES * 64)   // 565,504 qwords per batch

// truncated-IoU split: phase A computes row-tiles R < R_SPLIT (rows 0..1023);
// the tail (R >= R_SPLIT) is skipped per batch when the scan already kept 300.
#define R_SPLIT 16
#define ROWS_SPLIT (R_SPLIT * 64)  // 1024
#define G_HEAD 180                 // sum_{R=0..15} (101-R)>>3
#define G_TAIL (GT_TILES - G_HEAD) // 420
#define STATE_STRIDE 2048          // per-batch scan state (kept,done,supp,klist)
#define TMQ (ROWS_SPLIT * RT_TILES)            // 96,256 qwords per batch

// ---- workspace layout (bytes) ----
// KEYS and PHIST are dead by the time k_transpose runs; the row-major head
// mask (TMASK, 6,160,384 B) overlays them — no extra ws needed.
#define OFF_KEYS    0u             // 8*147456*4 = 4,718,592
#define OFF_PHIST   4718592u       // 8*4*16384*4 = 2,097,152 -> ends 6,815,744
#define OFF_TMASK   0u             // 8*96256*8 = 6,160,384 (overlay, late-use)
#define OFF_BOXES   6815744u       // 8*6000*4*4 = 768,000
#define OFF_BBRO    7583744u       // 8*16384*4 = 524,288 (read-only binbase)
#define OFF_BBMUT   8108032u       // 524,288 (scatter slot counters, swizzled)
#define OFF_CNT     8632320u       // thresh[8] + cnt[8] (512 B)
#define OFF_SEG     8632832u       // 8*8192*8 = 524,288
#define OFF_RIDX    9157120u       // 8*6000*4 = 192,000
#define OFF_STATE   9349120u       // 8*2048 = 16,384
#define OFF_MASK    9365504u       // 36,192,256 -> end 45,557,760
#define MASK_BYTES ((size_t)B_NUM * BQWORDS * 8)

__device__ __forceinline__ unsigned sortable_f32(float f) {
    unsigned u = __float_as_uint(f);
    return (u & 0x80000000u) ? ~u : (u | 0x80000000u);
}

// Decode one anchor's box exactly in the reference's op order.
__device__ __forceinline__ void decode_box(
    int b, int idx,
    const float* __restrict__ deltas, const float* __restrict__ im_info,
    const float* __restrict__ anchors,
    float& x1, float& y1, float& x2, float& y2, bool& valid)
{
    int a   = idx % A_NUM;
    int pix = idx / A_NUM;
    int w   = pix & (WW - 1);
    int h   = pix >> 7;

    float a0 = anchors[a * 4 + 0];
    float a1 = anchors[a * 4 + 1];
    float a2 = anchors[a * 4 + 2];
    float a3 = anchors[a * 4 + 3];

    float aw = __fadd_rn(__fsub_rn(a2, a0), 1.0f);
    float ah = __fadd_rn(__fsub_rn(a3, a1), 1.0f);
    float sx = (float)(w * FEAT_STRIDE_I);
    float sy = (float)(h * FEAT_STRIDE_I);
    float acx = __fadd_rn(__fadd_rn(sx, a0), __fmul_rn(0.5f, aw));
    float acy = __fadd_rn(__fadd_rn(sy, a1), __fmul_rn(0.5f, ah));

    size_t base = ((size_t)b * 36 + 4 * a) * NPIX + pix;
    float dx = deltas[base];
    float dy = deltas[base + NPIX];
    float dw = deltas[base + 2 * (size_t)NPIX];
    float dh = deltas[base + 3 * (size_t)NPIX];

    float pcx = __fadd_rn(__fmul_rn(dx, aw), acx);
    float pcy = __fadd_rn(__fmul_rn(dy, ah), acy);
    float pw  = __fmul_rn(expf(dw), aw);
    float ph  = __fmul_rn(expf(dh), ah);

    float hx = __fmul_rn(0.5f, pw);
    float hy = __fmul_rn(0.5f, ph);
    x1 = __fsub_rn(pcx, hx);
    y1 = __fsub_rn(pcy, hy);
    x2 = __fadd_rn(pcx, hx);
    y2 = __fadd_rn(pcy, hy);

    float im_h = im_info[b * 3 + 0];
    float im_w = im_info[b * 3 + 1];
    float sc   = im_info[b * 3 + 2];
    float wmax = __fsub_rn(im_w, 1.0f);
    float hmax = __fsub_rn(im_h, 1.0f);

    x1 = fminf(fmaxf(x1, 0.0f), wmax);
    y1 = fminf(fmaxf(y1, 0.0f), hmax);
    x2 = fminf(fmaxf(x2, 0.0f), wmax);
    y2 = fminf(fmaxf(y2, 0.0f), hmax);

    float min_sz = __fmul_rn(MIN_SIZE_F, sc);
    valid = (__fadd_rn(__fsub_rn(x2, x1), 1.0f) >= min_sz) &&
            (__fadd_rn(__fsub_rn(y2, y1), 1.0f) >= min_sz);
}

// K1: decode + masked score -> sortable key. Pure streaming, no atomics.
__global__ void k_decode(
    const float* __restrict__ scores, const float* __restrict__ deltas,
    const float* __restrict__ im_info, const float* __restrict__ anchors,
    unsigned* __restrict__ keys)
{
    int gt = blockIdx.x * blockDim.x + threadIdx.x;
    if (gt >= B_NUM * N_ANCH) return;
    int pix  = gt & (NPIX - 1);
    int rest = gt >> 14;
    int a = rest % A_NUM;
    int b = rest / A_NUM;
    int idx = pix * A_NUM + a;

    float x1, y1, x2, y2; bool valid;
    decode_box(b, idx, deltas, im_info, anchors, x1, y1, x2, y2, valid);

    float s = scores[((size_t)b * 18 + 9 + a) * NPIX + pix];
    if (!valid) s = NEG_INF_F;
    keys[gt] = sortable_f32(s);
}

// K2: partial histograms — 4 blocks per batch, each hists one quarter of
// the keys in a private LDS 16384-bin histogram (staged uint4 loads).
__global__ __launch_bounds__(1024) void k_hist_part(
    const unsigned* __restrict__ keys, unsigned* __restrict__ phist)
{
    __shared__ unsigned h[SWS(NBS - 1) + 2];   // 16896 words = 67.6 KB
    int b = blockIdx.x >> 2;
    int p = blockIdx.x & 3;
    int t = threadIdx.x;

    for (int i = t; i < SWS(NBS - 1) + 2; i += 1024) h[i] = 0u;
    __syncthreads();

    const uint4* kb4 = (const uint4*)(keys + (size_t)b * N_ANCH + p * QKEYS);
    uint4 v[9];
    #pragma unroll
    for (int k = 0; k < 9; ++k) v[k] = kb4[t + 1024 * k];
    #pragma unroll
    for (int k = 0; k < 9; ++k) {
        atomicAdd(&h[SWS(v[k].x >> 18)], 1u);
        atomicAdd(&h[SWS(v[k].y >> 18)], 1u);
        atomicAdd(&h[SWS(v[k].z >> 18)], 1u);
        atomicAdd(&h[SWS(v[k].w >> 18)], 1u);
    }
    __syncthreads();

    unsigned* ph = phist + (size_t)blockIdx.x * NBS;
    for (int i = t; i < NBS; i += 1024) ph[i] = h[SWS(i)];
}

// K3: per batch — sum 4 partials, suffix-scan 16384 bins, find threshold T.
// bbro linear (read by k_rank); bbmut written SWB-swizzled (scatter atomics).
__global__ __launch_bounds__(1024) void k_thresh2(
    const unsigned* __restrict__ phist, unsigned* __restrict__ bbro,
    unsigned* __restrict__ bbmut, unsigned* __restrict__ thresh,
    unsigned* __restrict__ cnt)
{
    __shared__ unsigned h[SWS(NBS - 1) + 2];
    __shared__ unsigned csum[1024];
    __shared__ unsigned sT;

    int b = blockIdx.x;
    int t = threadIdx.x;
    if (t == 0) sT = 0;

    const unsigned* ph = phist + (size_t)b * 4 * NBS;
    for (int i = t; i < NBS; i += 1024) {
        unsigned s0 = ph[i];
        unsigned s1 = ph[NBS + i];
        unsigned s2 = ph[2 * NBS + i];
        unsigned s3 = ph[3 * NBS + i];
        h[SWS(i)] = s0 + s1 + s2 + s3;
    }
    __syncthreads();

    int base = t * 16;
    unsigned s = 0;
    for (int u = 0; u < 16; ++u) s += h[SWS(base + u)];
    csum[t] = s;
    __syncthreads();
    for (int off = 1; off < 1024; off <<= 1) {
        unsigned v = (t + off < 1024) ? csum[t + off] : 0u;
        __syncthreads();
        csum[t] += v;
        __syncthreads();
    }
    unsigned before = csum[t] - s;

    unsigned acc = before;
    for (int bin = base + 15; bin >= base; --bin) {
        unsigned hh = h[SWS(bin)];
        if (acc + hh >= PRE_NMS) { atomicMax(&sT, (unsigned)bin); break; }
        acc += hh;
    }
    __syncthreads();
    unsigned T = sT;

    acc = before;
    for (int bin = base + 15; bin >= base; --bin) {
        unsigned hh = h[SWS(bin)];
        if ((unsigned)bin == T) cnt[b] = acc + hh;
        h[SWS(bin)] = acc;
        acc += hh;
    }
    if (t == 0) thresh[b] = T;
    __syncthreads();

    unsigned* r = bbro + (size_t)b * NBS;
    unsigned* m = bbmut + (size_t)b * NBS;
    for (int i = t; i < NBS; i += 1024) {
        unsigned v = h[SWS(i)];
        r[i] = v;
        m[SWB(i)] = v;
    }
}

// K4: bin-segmented scatter — slot allocated by atomicAdd on the SWIZZLED
// mutable binbase copy.
__global__ void k_scatter(
    const unsigned* __restrict__ keys, const unsigned* __restrict__ thresh,
    unsigned* __restrict__ bbmut, unsigned long long* __restrict__ seg)
{
    int gt = blockIdx.x * blockDim.x + threadIdx.x;
    int pix  = gt & (NPIX - 1);
    int rest = gt >> 14;
    int a = rest % A_NUM;
    int b = rest / A_NUM;

    unsigned key = keys[gt];
    unsigned bin = key >> 18;
    if (bin >= thresh[b]) {
        unsigned pos = atomicAdd(&bbmut[(size_t)b * NBS + SWB(bin)], 1u);
        if (pos < SEGL) {
            unsigned idx = (unsigned)(pix * A_NUM + a);
            seg[(size_t)b * SEGL + pos] =
                ((unsigned long long)key << 32) | (unsigned long long)(0xFFFFFFFFu - idx);
        }
    }
}

// K5a: many-block counting rank (32 blocks x 256 thr per batch, all CUs).
__global__ __launch_bounds__(256) void k_rank(
    const unsigned long long* __restrict__ seg, const unsigned* __restrict__ cnt,
    const unsigned* __restrict__ bbro, unsigned* __restrict__ ridx)
{
    int b = blockIdx.x >> 5;
    int p = ((blockIdx.x & 31) << 8) + threadIdx.x;
    unsigned n = cnt[b];
    if (n > SEGL) n = SEGL;
    if (p >= (int)n) return;

    const unsigned long long* S = seg + (size_t)b * SEGL;
    unsigned long long key = S[p];
    unsigned bin = (unsigned)(key >> 50);
    const unsigned* bb = bbro + (size_t)b * NBS;
    unsigned base = bb[bin];
    unsigned end = (bin > 0) ? bb[bin - 1] : n;
    if (end > n) end = n;

    unsigned rank = base;
    unsigned q = base;
    for (; q + 8 <= end; q += 8) {
        unsigned long long v0 = S[q + 0], v1 = S[q + 1];
        unsigned long long v2 = S[q + 2], v3 = S[q + 3];
        unsigned long long v4 = S[q + 4], v5 = S[q + 5];
        unsigned long long v6 = S[q + 6], v7 = S[q + 7];
        rank += (unsigned)(v0 > key) + (unsigned)(v1 > key)
              + (unsigned)(v2 > key) + (unsigned)(v3 > key)
              + (unsigned)(v4 > key) + (unsigned)(v5 > key)
              + (unsigned)(v6 > key) + (unsigned)(v7 > key);
    }
    for (; q < end; ++q) rank += (unsigned)(S[q] > key);

    if (rank < PRE_NMS)
        ridx[(size_t)b * PRE_NMS + rank] = 0xFFFFFFFFu - (unsigned)(key & 0xFFFFFFFFull);
}

// K5b: decode one box per output rank across all CUs.
__global__ void k_decode2(
    const unsigned* __restrict__ ridx,
    const float* __restrict__ deltas, const float* __restrict__ im_info,
    const float* __restrict__ anchors, float* __restrict__ boxes)
{
    int gt = blockIdx.x * blockDim.x + threadIdx.x;
    if (gt >= B_NUM * PRE_NMS) return;
    int b = gt / PRE_NMS;
    int idx = (int)ridx[gt];
    float x1, y1, x2, y2; bool v;
    decode_box(b, idx, deltas, im_info, anchors, x1, y1, x2, y2, v);
    *(float4*)(boxes + (size_t)gt * 4) = make_float4(x1, y1, x2, y2);
}

// One row of a 64x64 suppression block (exact ref op order; div only in the
// proven +-6e-7*uni band — validated absmax=0 since round 6).
__device__ __forceinline__ unsigned long long iou_row(
    float4 bi, float ia, float jx1, float jy1, float jx2, float jy2, float ja)
{
    float xx1 = fmaxf(bi.x, jx1);
    float yy1 = fmaxf(bi.y, jy1);
    float xx2 = fminf(bi.z, jx2);
    float yy2 = fminf(bi.w, jy2);
    float iw = fmaxf(0.0f, __fadd_rn(__fsub_rn(xx2, xx1), 1.0f));
    float ih = fmaxf(0.0f, __fadd_rn(__fsub_rn(yy2, yy1), 1.0f));
    float inter = __fmul_rn(iw, ih);
    float uni = __fsub_rn(__fadd_rn(ia, ja), inter);
    float diff = __fsub_rn(inter, __fmul_rn(NMS_THRESH_F, uni));
    unsigned long long sup = __ballot(diff > 0.0f);
    unsigned long long band = __ballot(fabsf(diff) <= __fmul_rn(6e-7f, uni));
    if (band) {
        unsigned long long supd = __ballot(__fdiv_rn(inter, uni) > NMS_THRESH_F);
        sup = (sup & ~band) | (supd & band);
    }
    return sup;
}

// K6: IoU suppression bitmask for row-tiles R in [Rstart, ...), ngroups
// 8-column groups per batch. statep!=null: skip batch if its scan already
// finished (done flag). Layout mask[b][R][C][64].
__global__ __launch_bounds__(256) void k_iou_mask(
    const float* __restrict__ boxes, unsigned long long* __restrict__ mask,
    int Rstart, int ngroups, const char* __restrict__ statep)
{
    int bid = blockIdx.x;
    int b = bid / ngroups;
    int g = bid - b * ngroups;
    if (statep && ((const int*)(statep + (size_t)b * STATE_STRIDE))[1]) return;

    int R = Rstart;
    while (g >= ((RT_TILES - R + 7) >> 3)) { g -= (RT_TILES - R + 7) >> 3; ++R; }

    int wave = threadIdx.x >> 6;
    int lane = threadIdx.x & 63;
    const float* Bb = boxes + (size_t)b * PRE_NMS * 4;

    __shared__ float4 rb4[64];
    __shared__ float rba[64];
    if (threadIdx.x < 64) {
        int il = R * 64 + threadIdx.x;
        float4 rv = make_float4(0.f, 0.f, -1.f, -1.f);
        if (il < PRE_NMS) rv = *(const float4*)(Bb + 4 * (size_t)il);
        rb4[threadIdx.x] = rv;
        rba[threadIdx.x] = __fmul_rn(__fadd_rn(__fsub_rn(rv.z, rv.x), 1.0f),
                                     __fadd_rn(__fsub_rn(rv.w, rv.y), 1.0f));
    }
    __syncthreads();

    int C1 = R + g * 8 + wave * 2;
    int C2 = C1 + 1;
    if (C1 >= RT_TILES) return;   // tail waves idle (no barriers below)

    float j1x1 = 0.f, j1y1 = 0.f, j1x2 = -1.f, j1y2 = -1.f;
    float j2x1 = 0.f, j2y1 = 0.f, j2x2 = -1.f, j2y2 = -1.f;
    int j1 = C1 * 64 + lane;
    int j2 = C2 * 64 + lane;
    if (j1 < PRE_NMS) {
        float4 v = *(const float4*)(Bb + 4 * (size_t)j1);
        j1x1 = v.x; j1y1 = v.y; j1x2 = v.z; j1y2 = v.w;
    }
    if (C2 < RT_TILES && j2 < PRE_NMS) {
        float4 v = *(const float4*)(Bb + 4 * (size_t)j2);
        j2x1 = v.x; j2y1 = v.y; j2x2 = v.z; j2y2 = v.w;
    }
    float j1a = __fmul_rn(__fadd_rn(__fsub_rn(j1x2, j1x1), 1.0f),
                          __fadd_rn(__fsub_rn(j1y2, j1y1), 1.0f));
    float j2a = __fmul_rn(__fadd_rn(__fsub_rn(j2x2, j2x1), 1.0f),
                          __fadd_rn(__fsub_rn(j2y2, j2y1), 1.0f));

    unsigned long long w1 = 0ULL, w2 = 0ULL;
    if (C1 == R) {   // diagonal tile
        #pragma unroll 4
        for (int ri = 0; ri < 64; ++ri) {
            float4 bi = rb4[ri];
            float ia = rba[ri];
            unsigned long long s1 = iou_row(bi, ia, j1x1, j1y1, j1x2, j1y2, j1a)
                                    & (0xFFFFFFFFFFFFFFFEull << ri);
            unsigned long long s2 = iou_row(bi, ia, j2x1, j2y1, j2x2, j2y2, j2a);
            w1 = (lane == ri) ? s1 : w1;
            w2 = (lane == ri) ? s2 : w2;
        }
    } else {
        #pragma unroll 4
        for (int ri = 0; ri < 64; ++ri) {
            float4 bi = rb4[ri];
            float ia = rba[ri];
            unsigned long long s1 = iou_row(bi, ia, j1x1, j1y1, j1x2, j1y2, j1a);
            unsigned long long s2 = iou_row(bi, ia, j2x1, j2y1, j2x2, j2y2, j2a);
            w1 = (lane == ri) ? s1 : w1;
            w2 = (lane == ri) ? s2 : w2;
        }
    }

    unsigned long long* Mb = mask + (size_t)b * BQWORDS;
    Mb[(size_t)(R * RT_TILES + C1) * 64 + lane] = w1;
    if (C2 < RT_TILES)
        Mb[(size_t)(R * RT_TILES + C2) * 64 + lane] = w2;
}

// K6b: transpose head mask [R][C][64] -> row-major tmask[i][C] for rows
// < ROWS_SPLIT.
__global__ __launch_bounds__(1024) void k_transpose(
    const unsigned long long* __restrict__ mask,
    unsigned long long* __restrict__ tmask)
{
    __shared__ unsigned long long tile[64 * RT_TILES];   // 48,128 B
    int b = blockIdx.x >> 4;
    int R = blockIdx.x & 15;
    int t = threadIdx.x;
    const unsigned long long* Mb =
        mask + (size_t)b * BQWORDS + (size_t)R * RT_TILES * 64;
    for (int idx = t; idx < RT_TILES * 64; idx += 1024) {
        int C = idx >> 6, r = idx & 63;
        tile[r * RT_TILES + C] = Mb[(size_t)C * 64 + r];
    }
    __syncthreads();
    unsigned long long* Tb =
        tmask + (size_t)b * TMQ + (size_t)R * 64 * RT_TILES;
    for (int idx = t; idx < 64 * RT_TILES; idx += 1024)
        Tb[idx] = tile[idx];
}

// K7: greedy scan, resumable. One wave/batch. Suppression state in
// registers (lane l owns words l, 64+l); curw via cross-lane shuffle.
// p1 (final_phase==0): round-24 row-major scan (best measured) with the
// prefetch window DEEPENED 16 -> 32 rows: the 56.6us/1024-row cost decomposed
// as ~10cy VALU + one L2-latency stall per prefetch group; 32-deep gives two
// groups of slack (~600+cy) to cover the ~500cy L2 round trip.
// (Tile-resolve variants from rounds 25/26 measured 57 and 61us - reverted.)
// p2 (final_phase==1): old per-row path on the strided mask layout.
__global__ __launch_bounds__(64) void k_nms_scan_part(
    const unsigned long long* __restrict__ mask,
    const unsigned long long* __restrict__ tmask,
    const float* __restrict__ boxes, float* __restrict__ out,
    char* __restrict__ statep, int row_begin, int row_end, int final_phase)
{
    const int b = blockIdx.x;
    const int l = threadIdx.x;
    char* st = statep + (size_t)b * STATE_STRIDE;
    int* s_meta = (int*)st;
    unsigned long long* s_supp = (unsigned long long*)(st + 16);
    int* s_klist = (int*)(st + 768);

    __shared__ int klist[POST_NMS];
    unsigned long long reg0, reg1;   // suppression words l and 64+l
    int kept, done;

    if (row_begin == 0) {
        reg0 = 0ULL; reg1 = 0ULL;
        kept = 0; done = 0;
    } else {
        kept = s_meta[0];
        done = s_meta[1];
        reg0 = s_supp[l];
        reg1 = (l < RT_TILES - 64) ? s_supp[64 + l] : 0ULL;
        for (int k = l; k < POST_NMS; k += 64) klist[k] = s_klist[k];
    }
    __syncthreads();

    const unsigned long long* __restrict__ M = mask + (size_t)b * BQWORDS;
    const unsigned long long* __restrict__ TM = tmask + (size_t)b * TMQ;
    unsigned long long curw = 0; int curwi = -1;

#define LOADROW_T(p0, p1, i) { \
        int _i = ((i) < ROWS_SPLIT) ? (i) : (ROWS_SPLIT - 1); \
        const unsigned long long* _r = TM + (size_t)_i * RT_TILES; \
        p0 = _r[l]; \
        p1 = (l < RT_TILES - 64) ? _r[64 + l] : 0ULL; }

#define LOADROW(p0, p1, i) { \
        int _i = ((i) < PRE_NMS) ? (i) : (PRE_NMS - 1); \
        int _R = _i >> 6; \
        const unsigned long long* _r = M + (size_t)(_R * RT_TILES) * 64 + (_i & 63); \
        p0 = 0ULL; p1 = 0ULL; \
        if (l >= _R) p0 = _r[l * 64]; \
        if (l < RT_TILES - 64 && 64 + l >= _R) p1 = _r[(64 + l) * 64]; }

#define STEP(i, p0, p1) { \
        if (kept < POST_NMS) { \
            int _wi = (i) >> 6; \
            if (_wi != curwi) { \
                curw = (_wi < 64) ? __shfl(reg0, _wi) : __shfl(reg1, _wi - 64); \
                curwi = _wi; \
            } \
            if (!((curw >> ((i) & 63)) & 1ULL)) { \
                if (l == 0) klist[kept] = (i); \
                unsigned long long _d = (_wi < 64) ? __shfl(p0, _wi) \
                                                   : __shfl(p1, _wi - 64); \
                reg0 |= p0; \
                reg1 |= p1; \
                curw |= _d; \
                ++kept; \
            } \
        } }

    if (!done && kept < POST_NMS) {
        if (!final_phase) {
            unsigned long long p[32][2];
            #pragma unroll
            for (int k = 0; k < 32; ++k) { LOADROW_T(p[k][0], p[k][1], row_begin + k) }
            for (int i = row_begin; i < row_end && kept < POST_NMS; i += 32) {
                #pragma unroll
                for (int k = 0; k < 32; ++k) {
                    STEP(i + k, p[k][0], p[k][1])
                    LOADROW_T(p[k][0], p[k][1], i + 32 + k)
                }
            }
        } else {
            unsigned long long p[16][2];
            #pragma unroll
            for (int k = 0; k < 16; ++k) { LOADROW(p[k][0], p[k][1], row_begin + k) }
            for (int i = row_begin; i < row_end && kept < POST_NMS; i += 16) {
                #pragma unroll
                for (int k = 0; k < 16; ++k) {
                    STEP(i + k, p[k][0], p[k][1])
                    LOADROW(p[k][0], p[k][1], i + 16 + k)
                }
            }
        }
    }
    __syncthreads();

    if (!final_phase) {
        if (l == 0) { s_meta[0] = kept; s_meta[1] = (kept >= POST_NMS) ? 1 : 0; }
        s_supp[l] = reg0;
        if (l < RT_TILES - 64) s_supp[64 + l] = reg1;
        for (int k = l; k < POST_NMS; k += 64) s_klist[k] = klist[k];
    } else {
        for (int k = l; k < POST_NMS; k += 64) {
            size_t o = ((size_t)b * POST_NMS + k) * 5;
            float x1 = 0.f, y1 = 0.f, x2 = 0.f, y2 = 0.f;
            if (k < kept) {
                int idx = klist[k];
                const float4 v = *(const float4*)(boxes + ((size_t)b * PRE_NMS + idx) * 4);
                x1 = v.x; y1 = v.y; x2 = v.z; y2 = v.w;
            }
            out[o + 0] = (float)b;
            out[o + 1] = x1; out[o + 2] = y1; out[o + 3] = x2; out[o + 4] = y2;
        }
    }
#undef LOADROW_T
#undef LOADROW
#undef STEP
}

// Fallback NMS (used only if ws_size is too small for the bitmask).
__global__ __launch_bounds__(1024) void k_nms_out(
    const float* __restrict__ boxes, float* __restrict__ out)
{
    __shared__ float bx1[PRE_NMS], by1[PRE_NMS], bx2[PRE_NMS], by2[PRE_NMS], bar[PRE_NMS];
    __shared__ unsigned rem[(PRE_NMS + 31) / 32];
    __shared__ int kept_idx[POST_NMS];

    int b = blockIdx.x;
    int t = threadIdx.x;

    for (int p = t; p < PRE_NMS; p += 1024) {
        size_t o = ((size_t)b * PRE_NMS + p) * 4;
        float x1 = boxes[o], y1 = boxes[o + 1], x2 = boxes[o + 2], y2 = boxes[o + 3];
        bx1[p] = x1; by1[p] = y1; bx2[p] = x2; by2[p] = y2;
        bar[p] = __fmul_rn(__fadd_rn(__fsub_rn(x2, x1), 1.0f),
                           __fadd_rn(__fsub_rn(y2, y1), 1.0f));
    }
    for (int p = t; p < (PRE_NMS + 31) / 32; p += 1024) rem[p] = 0u;
    __syncthreads();

    int kept = 0;
    for (int i = 0; i < PRE_NMS && kept < POST_NMS; ++i) {
        if (rem[i >> 5] & (1u << (i & 31))) continue;
        if (t == 0) kept_idx[kept] = i;
        float xi1 = bx1[i], yi1 = by1[i], xi2 = bx2[i], yi2 = by2[i], ai = bar[i];
        for (int j = i + 1 + t; j < PRE_NMS; j += 1024) {
            float xx1 = fmaxf(xi1, bx1[j]);
            float yy1 = fmaxf(yi1, by1[j]);
            float xx2 = fminf(xi2, bx2[j]);
            float yy2 = fminf(yi2, by2[j]);
            float iw = fmaxf(0.0f, __fadd_rn(__fsub_rn(xx2, xx1), 1.0f));
            float ih = fmaxf(0.0f, __fadd_rn(__fsub_rn(yy2, yy1), 1.0f));
            float inter = __fmul_rn(iw, ih);
            if (inter > 0.0f) {
                float uni = __fsub_rn(__fadd_rn(ai, bar[j]), inter);
                float iou = __fdiv_rn(inter, uni);
                if (iou > NMS_THRESH_F) atomicOr(&rem[j >> 5], 1u << (j & 31));
            }
        }
        ++kept;
        __syncthreads();
    }

    for (int k = t; k < POST_NMS; k += 1024) {
        size_t o = ((size_t)b * POST_NMS + k) * 5;
        out[o] = (float)b;
        if (k < kept) {
            int ii = kept_idx[k];
            out[o + 1] = bx1[ii]; out[o + 2] = by1[ii];
            out[o + 3] = bx2[ii]; out[o + 4] = by2[ii];
        } else {
            out[o + 1] = 0.0f; out[o + 2] = 0.0f; out[o + 3] = 0.0f; out[o + 4] = 0.0f;
        }
    }
}

extern "C" void kernel_launch(void* const* d_in, const int* in_sizes, int n_in,
                              void* d_out, int out_size, void* d_ws, size_t ws_size,
                              hipStream_t stream)
{
    const float* scores  = (const float*)d_in[0];
    const float* deltas  = (const float*)d_in[1];
    const float* im_info = (const float*)d_in[2];
    const float* anchors = (const float*)d_in[3];
    float* out = (float*)d_out;
    char* ws = (char*)d_ws;

    unsigned* keys             = (unsigned*)(ws + OFF_KEYS);
    unsigned* phist            = (unsigned*)(ws + OFF_PHIST);
    unsigned long long* tmask  = (unsigned long long*)(ws + OFF_TMASK);
    float* boxes               = (float*)(ws + OFF_BOXES);
    unsigned* bbro             = (unsigned*)(ws + OFF_BBRO);
    unsigned* bbmut            = (unsigned*)(ws + OFF_BBMUT);
    unsigned* thresh           = (unsigned*)(ws + OFF_CNT);
    unsigned* cnt              = thresh + 8;
    unsigned long long* seg    = (unsigned long long*)(ws + OFF_SEG);
    unsigned* ridx             = (unsigned*)(ws + OFF_RIDX);
    char* state                = (char*)(ws + OFF_STATE);
    unsigned long long* mask   = (unsigned long long*)(ws + OFF_MASK);

    int total = B_NUM * N_ANCH;
    int blk = 256;
    k_decode<<<(total + blk - 1) / blk, blk, 0, stream>>>(
        scores, deltas, im_info, anchors, keys);
    k_hist_part<<<B_NUM * 4, 1024, 0, stream>>>(keys, phist);
    k_thresh2<<<B_NUM, 1024, 0, stream>>>(phist, bbro, bbmut, thresh, cnt);
    k_scatter<<<(total + blk - 1) / blk, blk, 0, stream>>>(
        keys, thresh, bbmut, seg);
    k_rank<<<B_NUM * 32, 256, 0, stream>>>(seg, cnt, bbro, ridx);
    k_decode2<<<(B_NUM * PRE_NMS + blk - 1) / blk, blk, 0, stream>>>(
        ridx, deltas, im_info, anchors, boxes);

    if (ws_size >= (size_t)OFF_MASK + MASK_BYTES) {
        // phase A: rows 0..1023 only
        k_iou_mask<<<B_NUM * G_HEAD, 256, 0, stream>>>(
            boxes, mask, 0, G_HEAD, (const char*)0);
        // transpose head rows to row-major (overlays dead keys/phist)
        k_transpose<<<B_NUM * R_SPLIT, 1024, 0, stream>>>(mask, tmask);
        // scan p1: row-major scan, 32-deep prefetch
        k_nms_scan_part<<<B_NUM, 64, 0, stream>>>(
            mask, tmask, boxes, out, state, 0, ROWS_SPLIT, 0);
        // tail: rows >= 1024, skipped per batch when done
        k_iou_mask<<<B_NUM * G_TAIL, 256, 0, stream>>>(
            boxes, mask, R_SPLIT, G_TAIL, (const char*)state);
        // scan p2: finish (or just write output if already done)
        k_nms_scan_part<<<B_NUM, 64, 0, stream>>>(
            mask, tmask, boxes, out, state, ROWS_SPLIT, PRE_NMS, 1);
    } else {
        k_nms_out<<<B_NUM, 1024, 0, stream>>>(boxes, out);
    }
}

// Round 28
// 167.712 us; speedup vs baseline: 1.0451x; 1.0272x over previous
//
#include <hip/hip_runtime.h>
#include <stdint.h>

#define FEAT_STRIDE_I 16
#define A_NUM 9
#define HH 128
#define WW 128
#define NPIX (HH * WW)            // 16384
#define N_ANCH (NPIX * A_NUM)     // 147456
#define B_NUM 8
#define PRE_NMS 6000
#define POST_NMS 300
#define NMS_THRESH_F 0.7f
#define MIN_SIZE_F 16.0f
#define NEG_INF_F -1e30f

#define NBS 16384                  // 14-bit bins (key>>18)
#define SWS(i) ((i) + ((i) >> 5))  // LDS swizzle
// cache-line spread for the mutable bin counters (round 24: -45us on scatter)
#define SWB(bin) ((((bin) & 1023) << 4) | ((bin) >> 10))
#define SEGL 8192                  // candidate segment cap (cnt ~6700 max)
#define QKEYS (N_ANCH / 4)         // 36864 keys per hist part

#define RT_TILES 94                // ceil(6000/64)
#define GT_TILES 600               // sum_R ceil((94-R)/8): 8-column groups
#define BQWORDS (RT_TILES * RT_TILES * 64)   // 565,504 qwords per batch

// truncated-IoU split: phase A computes row-tiles R < R_SPLIT (rows 0..1023);
// the tail (R >= R_SPLIT) is skipped per batch when the scan already kept 300.
#define R_SPLIT 16
#define ROWS_SPLIT (R_SPLIT * 64)  // 1024
#define G_HEAD 180                 // sum_{R=0..15} (101-R)>>3
#define G_TAIL (GT_TILES - G_HEAD) // 420
#define STATE_STRIDE 2048          // per-batch scan state (kept,done,supp,klist)
#define TMQ (ROWS_SPLIT * RT_TILES)            // 96,256 qwords per batch

// ---- workspace layout (bytes) ----
// KEYS and PHIST are dead by the time k_transpose runs; the row-major head
// mask (TMASK, 6,160,384 B) overlays them — no extra ws needed.
#define OFF_KEYS    0u             // 8*147456*4 = 4,718,592
#define OFF_PHIST   4718592u       // 8*4*16384*4 = 2,097,152 -> ends 6,815,744
#define OFF_TMASK   0u             // 8*96256*8 = 6,160,384 (overlay, late-use)
#define OFF_BOXES   6815744u       // 8*6000*4*4 = 768,000
#define OFF_BBRO    7583744u       // 8*16384*4 = 524,288 (read-only binbase)
#define OFF_BBMUT   8108032u       // 524,288 (scatter slot counters, swizzled)
#define OFF_CNT     8632320u       // thresh[8] + cnt[8] (512 B)
#define OFF_SEG     8632832u       // 8*8192*8 = 524,288
#define OFF_RIDX    9157120u       // 8*6000*4 = 192,000
#define OFF_STATE   9349120u       // 8*2048 = 16,384
#define OFF_DIAG    9365504u       // 8*1024*8 = 65,536 (diagonal words)
#define OFF_MASK    9431040u       // 36,192,256 -> end 45,623,296
#define MASK_BYTES ((size_t)B_NUM * BQWORDS * 8)

__device__ __forceinline__ unsigned sortable_f32(float f) {
    unsigned u = __float_as_uint(f);
    return (u & 0x80000000u) ? ~u : (u | 0x80000000u);
}

// Decode one anchor's box exactly in the reference's op order.
__device__ __forceinline__ void decode_box(
    int b, int idx,
    const float* __restrict__ deltas, const float* __restrict__ im_info,
    const float* __restrict__ anchors,
    float& x1, float& y1, float& x2, float& y2, bool& valid)
{
    int a   = idx % A_NUM;
    int pix = idx / A_NUM;
    int w   = pix & (WW - 1);
    int h   = pix >> 7;

    float a0 = anchors[a * 4 + 0];
    float a1 = anchors[a * 4 + 1];
    float a2 = anchors[a * 4 + 2];
    float a3 = anchors[a * 4 + 3];

    float aw = __fadd_rn(__fsub_rn(a2, a0), 1.0f);
    float ah = __fadd_rn(__fsub_rn(a3, a1), 1.0f);
    float sx = (float)(w * FEAT_STRIDE_I);
    float sy = (float)(h * FEAT_STRIDE_I);
    float acx = __fadd_rn(__fadd_rn(sx, a0), __fmul_rn(0.5f, aw));
    float acy = __fadd_rn(__fadd_rn(sy, a1), __fmul_rn(0.5f, ah));

    size_t base = ((size_t)b * 36 + 4 * a) * NPIX + pix;
    float dx = deltas[base];
    float dy = deltas[base + NPIX];
    float dw = deltas[base + 2 * (size_t)NPIX];
    float dh = deltas[base + 3 * (size_t)NPIX];

    float pcx = __fadd_rn(__fmul_rn(dx, aw), acx);
    float pcy = __fadd_rn(__fmul_rn(dy, ah), acy);
    float pw  = __fmul_rn(expf(dw), aw);
    float ph  = __fmul_rn(expf(dh), ah);

    float hx = __fmul_rn(0.5f, pw);
    float hy = __fmul_rn(0.5f, ph);
    x1 = __fsub_rn(pcx, hx);
    y1 = __fsub_rn(pcy, hy);
    x2 = __fadd_rn(pcx, hx);
    y2 = __fadd_rn(pcy, hy);

    float im_h = im_info[b * 3 + 0];
    float im_w = im_info[b * 3 + 1];
    float sc   = im_info[b * 3 + 2];
    float wmax = __fsub_rn(im_w, 1.0f);
    float hmax = __fsub_rn(im_h, 1.0f);

    x1 = fminf(fmaxf(x1, 0.0f), wmax);
    y1 = fminf(fmaxf(y1, 0.0f), hmax);
    x2 = fminf(fmaxf(x2, 0.0f), wmax);
    y2 = fminf(fmaxf(y2, 0.0f), hmax);

    float min_sz = __fmul_rn(MIN_SIZE_F, sc);
    valid = (__fadd_rn(__fsub_rn(x2, x1), 1.0f) >= min_sz) &&
            (__fadd_rn(__fsub_rn(y2, y1), 1.0f) >= min_sz);
}

// K1: decode + masked score -> sortable key. Pure streaming, no atomics.
__global__ void k_decode(
    const float* __restrict__ scores, const float* __restrict__ deltas,
    const float* __restrict__ im_info, const float* __restrict__ anchors,
    unsigned* __restrict__ keys)
{
    int gt = blockIdx.x * blockDim.x + threadIdx.x;
    if (gt >= B_NUM * N_ANCH) return;
    int pix  = gt & (NPIX - 1);
    int rest = gt >> 14;
    int a = rest % A_NUM;
    int b = rest / A_NUM;
    int idx = pix * A_NUM + a;

    float x1, y1, x2, y2; bool valid;
    decode_box(b, idx, deltas, im_info, anchors, x1, y1, x2, y2, valid);

    float s = scores[((size_t)b * 18 + 9 + a) * NPIX + pix];
    if (!valid) s = NEG_INF_F;
    keys[gt] = sortable_f32(s);
}

// K2: partial histograms — 4 blocks per batch, each hists one quarter of
// the keys in a private LDS 16384-bin histogram (staged uint4 loads).
__global__ __launch_bounds__(1024) void k_hist_part(
    const unsigned* __restrict__ keys, unsigned* __restrict__ phist)
{
    __shared__ unsigned h[SWS(NBS - 1) + 2];   // 16896 words = 67.6 KB
    int b = blockIdx.x >> 2;
    int p = blockIdx.x & 3;
    int t = threadIdx.x;

    for (int i = t; i < SWS(NBS - 1) + 2; i += 1024) h[i] = 0u;
    __syncthreads();

    const uint4* kb4 = (const uint4*)(keys + (size_t)b * N_ANCH + p * QKEYS);
    uint4 v[9];
    #pragma unroll
    for (int k = 0; k < 9; ++k) v[k] = kb4[t + 1024 * k];
    #pragma unroll
    for (int k = 0; k < 9; ++k) {
        atomicAdd(&h[SWS(v[k].x >> 18)], 1u);
        atomicAdd(&h[SWS(v[k].y >> 18)], 1u);
        atomicAdd(&h[SWS(v[k].z >> 18)], 1u);
        atomicAdd(&h[SWS(v[k].w >> 18)], 1u);
    }
    __syncthreads();

    unsigned* ph = phist + (size_t)blockIdx.x * NBS;
    for (int i = t; i < NBS; i += 1024) ph[i] = h[SWS(i)];
}

// K3: per batch — sum 4 partials, suffix-scan 16384 bins, find threshold T.
// bbro linear (read by k_rank); bbmut written SWB-swizzled (scatter atomics).
__global__ __launch_bounds__(1024) void k_thresh2(
    const unsigned* __restrict__ phist, unsigned* __restrict__ bbro,
    unsigned* __restrict__ bbmut, unsigned* __restrict__ thresh,
    unsigned* __restrict__ cnt)
{
    __shared__ unsigned h[SWS(NBS - 1) + 2];
    __shared__ unsigned csum[1024];
    __shared__ unsigned sT;

    int b = blockIdx.x;
    int t = threadIdx.x;
    if (t == 0) sT = 0;

    const unsigned* ph = phist + (size_t)b * 4 * NBS;
    for (int i = t; i < NBS; i += 1024) {
        unsigned s0 = ph[i];
        unsigned s1 = ph[NBS + i];
        unsigned s2 = ph[2 * NBS + i];
        unsigned s3 = ph[3 * NBS + i];
        h[SWS(i)] = s0 + s1 + s2 + s3;
    }
    __syncthreads();

    int base = t * 16;
    unsigned s = 0;
    for (int u = 0; u < 16; ++u) s += h[SWS(base + u)];
    csum[t] = s;
    __syncthreads();
    for (int off = 1; off < 1024; off <<= 1) {
        unsigned v = (t + off < 1024) ? csum[t + off] : 0u;
        __syncthreads();
        csum[t] += v;
        __syncthreads();
    }
    unsigned before = csum[t] - s;

    unsigned acc = before;
    for (int bin = base + 15; bin >= base; --bin) {
        unsigned hh = h[SWS(bin)];
        if (acc + hh >= PRE_NMS) { atomicMax(&sT, (unsigned)bin); break; }
        acc += hh;
    }
    __syncthreads();
    unsigned T = sT;

    acc = before;
    for (int bin = base + 15; bin >= base; --bin) {
        unsigned hh = h[SWS(bin)];
        if ((unsigned)bin == T) cnt[b] = acc + hh;
        h[SWS(bin)] = acc;
        acc += hh;
    }
    if (t == 0) thresh[b] = T;
    __syncthreads();

    unsigned* r = bbro + (size_t)b * NBS;
    unsigned* m = bbmut + (size_t)b * NBS;
    for (int i = t; i < NBS; i += 1024) {
        unsigned v = h[SWS(i)];
        r[i] = v;
        m[SWB(i)] = v;
    }
}

// K4: bin-segmented scatter — slot allocated by atomicAdd on the SWIZZLED
// mutable binbase copy.
__global__ void k_scatter(
    const unsigned* __restrict__ keys, const unsigned* __restrict__ thresh,
    unsigned* __restrict__ bbmut, unsigned long long* __restrict__ seg)
{
    int gt = blockIdx.x * blockDim.x + threadIdx.x;
    int pix  = gt & (NPIX - 1);
    int rest = gt >> 14;
    int a = rest % A_NUM;
    int b = rest / A_NUM;

    unsigned key = keys[gt];
    unsigned bin = key >> 18;
    if (bin >= thresh[b]) {
        unsigned pos = atomicAdd(&bbmut[(size_t)b * NBS + SWB(bin)], 1u);
        if (pos < SEGL) {
            unsigned idx = (unsigned)(pix * A_NUM + a);
            seg[(size_t)b * SEGL + pos] =
                ((unsigned long long)key << 32) | (unsigned long long)(0xFFFFFFFFu - idx);
        }
    }
}

// K5a: many-block counting rank (32 blocks x 256 thr per batch, all CUs).
__global__ __launch_bounds__(256) void k_rank(
    const unsigned long long* __restrict__ seg, const unsigned* __restrict__ cnt,
    const unsigned* __restrict__ bbro, unsigned* __restrict__ ridx)
{
    int b = blockIdx.x >> 5;
    int p = ((blockIdx.x & 31) << 8) + threadIdx.x;
    unsigned n = cnt[b];
    if (n > SEGL) n = SEGL;
    if (p >= (int)n) return;

    const unsigned long long* S = seg + (size_t)b * SEGL;
    unsigned long long key = S[p];
    unsigned bin = (unsigned)(key >> 50);
    const unsigned* bb = bbro + (size_t)b * NBS;
    unsigned base = bb[bin];
    unsigned end = (bin > 0) ? bb[bin - 1] : n;
    if (end > n) end = n;

    unsigned rank = base;
    unsigned q = base;
    for (; q + 8 <= end; q += 8) {
        unsigned long long v0 = S[q + 0], v1 = S[q + 1];
        unsigned long long v2 = S[q + 2], v3 = S[q + 3];
        unsigned long long v4 = S[q + 4], v5 = S[q + 5];
        unsigned long long v6 = S[q + 6], v7 = S[q + 7];
        rank += (unsigned)(v0 > key) + (unsigned)(v1 > key)
              + (unsigned)(v2 > key) + (unsigned)(v3 > key)
              + (unsigned)(v4 > key) + (unsigned)(v5 > key)
              + (unsigned)(v6 > key) + (unsigned)(v7 > key);
    }
    for (; q < end; ++q) rank += (unsigned)(S[q] > key);

    if (rank < PRE_NMS)
        ridx[(size_t)b * PRE_NMS + rank] = 0xFFFFFFFFu - (unsigned)(key & 0xFFFFFFFFull);
}

// K5b: decode one box per output rank across all CUs.
__global__ void k_decode2(
    const unsigned* __restrict__ ridx,
    const float* __restrict__ deltas, const float* __restrict__ im_info,
    const float* __restrict__ anchors, float* __restrict__ boxes)
{
    int gt = blockIdx.x * blockDim.x + threadIdx.x;
    if (gt >= B_NUM * PRE_NMS) return;
    int b = gt / PRE_NMS;
    int idx = (int)ridx[gt];
    float x1, y1, x2, y2; bool v;
    decode_box(b, idx, deltas, im_info, anchors, x1, y1, x2, y2, v);
    *(float4*)(boxes + (size_t)gt * 4) = make_float4(x1, y1, x2, y2);
}

// One row of a 64x64 suppression block (exact ref op order; div only in the
// proven +-6e-7*uni band — validated absmax=0 since round 6).
__device__ __forceinline__ unsigned long long iou_row(
    float4 bi, float ia, float jx1, float jy1, float jx2, float jy2, float ja)
{
    float xx1 = fmaxf(bi.x, jx1);
    float yy1 = fmaxf(bi.y, jy1);
    float xx2 = fminf(bi.z, jx2);
    float yy2 = fminf(bi.w, jy2);
    float iw = fmaxf(0.0f, __fadd_rn(__fsub_rn(xx2, xx1), 1.0f));
    float ih = fmaxf(0.0f, __fadd_rn(__fsub_rn(yy2, yy1), 1.0f));
    float inter = __fmul_rn(iw, ih);
    float uni = __fsub_rn(__fadd_rn(ia, ja), inter);
    float diff = __fsub_rn(inter, __fmul_rn(NMS_THRESH_F, uni));
    unsigned long long sup = __ballot(diff > 0.0f);
    unsigned long long band = __ballot(fabsf(diff) <= __fmul_rn(6e-7f, uni));
    if (band) {
        unsigned long long supd = __ballot(__fdiv_rn(inter, uni) > NMS_THRESH_F);
        sup = (sup & ~band) | (supd & band);
    }
    return sup;
}

// K6: IoU suppression bitmask for row-tiles R in [Rstart, ...), ngroups
// 8-column groups per batch. statep!=null: skip batch if its scan already
// finished (done flag). Layout mask[b][R][C][64].
__global__ __launch_bounds__(256) void k_iou_mask(
    const float* __restrict__ boxes, unsigned long long* __restrict__ mask,
    int Rstart, int ngroups, const char* __restrict__ statep)
{
    int bid = blockIdx.x;
    int b = bid / ngroups;
    int g = bid - b * ngroups;
    if (statep && ((const int*)(statep + (size_t)b * STATE_STRIDE))[1]) return;

    int R = Rstart;
    while (g >= ((RT_TILES - R + 7) >> 3)) { g -= (RT_TILES - R + 7) >> 3; ++R; }

    int wave = threadIdx.x >> 6;
    int lane = threadIdx.x & 63;
    const float* Bb = boxes + (size_t)b * PRE_NMS * 4;

    __shared__ float4 rb4[64];
    __shared__ float rba[64];
    if (threadIdx.x < 64) {
        int il = R * 64 + threadIdx.x;
        float4 rv = make_float4(0.f, 0.f, -1.f, -1.f);
        if (il < PRE_NMS) rv = *(const float4*)(Bb + 4 * (size_t)il);
        rb4[threadIdx.x] = rv;
        rba[threadIdx.x] = __fmul_rn(__fadd_rn(__fsub_rn(rv.z, rv.x), 1.0f),
                                     __fadd_rn(__fsub_rn(rv.w, rv.y), 1.0f));
    }
    __syncthreads();

    int C1 = R + g * 8 + wave * 2;
    int C2 = C1 + 1;
    if (C1 >= RT_TILES) return;   // tail waves idle (no barriers below)

    float j1x1 = 0.f, j1y1 = 0.f, j1x2 = -1.f, j1y2 = -1.f;
    float j2x1 = 0.f, j2y1 = 0.f, j2x2 = -1.f, j2y2 = -1.f;
    int j1 = C1 * 64 + lane;
    int j2 = C2 * 64 + lane;
    if (j1 < PRE_NMS) {
        float4 v = *(const float4*)(Bb + 4 * (size_t)j1);
        j1x1 = v.x; j1y1 = v.y; j1x2 = v.z; j1y2 = v.w;
    }
    if (C2 < RT_TILES && j2 < PRE_NMS) {
        float4 v = *(const float4*)(Bb + 4 * (size_t)j2);
        j2x1 = v.x; j2y1 = v.y; j2x2 = v.z; j2y2 = v.w;
    }
    float j1a = __fmul_rn(__fadd_rn(__fsub_rn(j1x2, j1x1), 1.0f),
                          __fadd_rn(__fsub_rn(j1y2, j1y1), 1.0f));
    float j2a = __fmul_rn(__fadd_rn(__fsub_rn(j2x2, j2x1), 1.0f),
                          __fadd_rn(__fsub_rn(j2y2, j2y1), 1.0f));

    unsigned long long w1 = 0ULL, w2 = 0ULL;
    if (C1 == R) {   // diagonal tile
        #pragma unroll 4
        for (int ri = 0; ri < 64; ++ri) {
            float4 bi = rb4[ri];
            float ia = rba[ri];
            unsigned long long s1 = iou_row(bi, ia, j1x1, j1y1, j1x2, j1y2, j1a)
                                    & (0xFFFFFFFFFFFFFFFEull << ri);
            unsigned long long s2 = iou_row(bi, ia, j2x1, j2y1, j2x2, j2y2, j2a);
            w1 = (lane == ri) ? s1 : w1;
            w2 = (lane == ri) ? s2 : w2;
        }
    } else {
        #pragma unroll 4
        for (int ri = 0; ri < 64; ++ri) {
            float4 bi = rb4[ri];
            float ia = rba[ri];
            unsigned long long s1 = iou_row(bi, ia, j1x1, j1y1, j1x2, j1y2, j1a);
            unsigned long long s2 = iou_row(bi, ia, j2x1, j2y1, j2x2, j2y2, j2a);
            w1 = (lane == ri) ? s1 : w1;
            w2 = (lane == ri) ? s2 : w2;
        }
    }

    unsigned long long* Mb = mask + (size_t)b * BQWORDS;
    Mb[(size_t)(R * RT_TILES + C1) * 64 + lane] = w1;
    if (C2 < RT_TILES)
        Mb[(size_t)(R * RT_TILES + C2) * 64 + lane] = w2;
}

// K6b: transpose head mask [R][C][64] -> row-major tmask[i][C] for rows
// < ROWS_SPLIT; also emit diagw[i] = tmask[i][i>>6] (the row's own-tile
// suppression word) so the scan's kept-row update needs no cross-lane
// shuffle (round-27: the 2-bpermute chain per kept row was the ~50us floor).
__global__ __launch_bounds__(1024) void k_transpose(
    const unsigned long long* __restrict__ mask,
    unsigned long long* __restrict__ tmask,
    unsigned long long* __restrict__ diagw)
{
    __shared__ unsigned long long tile[64 * RT_TILES];   // 48,128 B
    int b = blockIdx.x >> 4;
    int R = blockIdx.x & 15;
    int t = threadIdx.x;
    const unsigned long long* Mb =
        mask + (size_t)b * BQWORDS + (size_t)R * RT_TILES * 64;
    for (int idx = t; idx < RT_TILES * 64; idx += 1024) {
        int C = idx >> 6, r = idx & 63;
        tile[r * RT_TILES + C] = Mb[(size_t)C * 64 + r];
    }
    __syncthreads();
    unsigned long long* Tb =
        tmask + (size_t)b * TMQ + (size_t)R * 64 * RT_TILES;
    for (int idx = t; idx < 64 * RT_TILES; idx += 1024)
        Tb[idx] = tile[idx];
    if (t < 64)
        diagw[(size_t)b * ROWS_SPLIT + R * 64 + t] = tile[t * RT_TILES + R];
}

// K7: greedy scan, resumable. One wave/batch. Suppression state in
// registers (lane l owns words l, 64+l).
// p1 (final_phase==0): row-major scan; kept-row curw update uses the
// PREFETCHED diagonal word (no shuffle on the serial chain — only 16
// tile-boundary shuffles). Sequential-scan identity: the window word
// _wi = i>>6 equals row i's own tile, so the only word of row i that
// curw ever needs is diagw[i] = tmask[i][i>>6].
// p2 (final_phase==1): old per-row path on the strided mask layout.
__global__ __launch_bounds__(64) void k_nms_scan_part(
    const unsigned long long* __restrict__ mask,
    const unsigned long long* __restrict__ tmask,
    const unsigned long long* __restrict__ diagw,
    const float* __restrict__ boxes, float* __restrict__ out,
    char* __restrict__ statep, int row_begin, int row_end, int final_phase)
{
    const int b = blockIdx.x;
    const int l = threadIdx.x;
    char* st = statep + (size_t)b * STATE_STRIDE;
    int* s_meta = (int*)st;
    unsigned long long* s_supp = (unsigned long long*)(st + 16);
    int* s_klist = (int*)(st + 768);

    __shared__ int klist[POST_NMS];
    unsigned long long reg0, reg1;   // suppression words l and 64+l
    int kept, done;

    if (row_begin == 0) {
        reg0 = 0ULL; reg1 = 0ULL;
        kept = 0; done = 0;
    } else {
        kept = s_meta[0];
        done = s_meta[1];
        reg0 = s_supp[l];
        reg1 = (l < RT_TILES - 64) ? s_supp[64 + l] : 0ULL;
        for (int k = l; k < POST_NMS; k += 64) klist[k] = s_klist[k];
    }
    __syncthreads();

    const unsigned long long* __restrict__ M = mask + (size_t)b * BQWORDS;
    const unsigned long long* __restrict__ TM = tmask + (size_t)b * TMQ;
    const unsigned long long* __restrict__ DW = diagw + (size_t)b * ROWS_SPLIT;
    unsigned long long curw = 0; int curwi = -1;

#define LOADROW_T(p0, p1, dwv, i) { \
        int _i = ((i) < ROWS_SPLIT) ? (i) : (ROWS_SPLIT - 1); \
        const unsigned long long* _r = TM + (size_t)_i * RT_TILES; \
        p0 = _r[l]; \
        p1 = (l < RT_TILES - 64) ? _r[64 + l] : 0ULL; \
        dwv = DW[_i]; }

#define STEP_T(i, p0, p1, dwv) { \
        if (kept < POST_NMS) { \
            int _wi = (i) >> 6; \
            if (_wi != curwi) { \
                curw = __shfl(reg0, _wi); \
                curwi = _wi; \
            } \
            if (!((curw >> ((i) & 63)) & 1ULL)) { \
                if (l == 0) klist[kept] = (i); \
                reg0 |= p0; \
                reg1 |= p1; \
                curw |= dwv; \
                ++kept; \
            } \
        } }

#define LOADROW(p0, p1, i) { \
        int _i = ((i) < PRE_NMS) ? (i) : (PRE_NMS - 1); \
        int _R = _i >> 6; \
        const unsigned long long* _r = M + (size_t)(_R * RT_TILES) * 64 + (_i & 63); \
        p0 = 0ULL; p1 = 0ULL; \
        if (l >= _R) p0 = _r[l * 64]; \
        if (l < RT_TILES - 64 && 64 + l >= _R) p1 = _r[(64 + l) * 64]; }

#define STEP(i, p0, p1) { \
        if (kept < POST_NMS) { \
            int _wi = (i) >> 6; \
            if (_wi != curwi) { \
                curw = (_wi < 64) ? __shfl(reg0, _wi) : __shfl(reg1, _wi - 64); \
                curwi = _wi; \
            } \
            if (!((curw >> ((i) & 63)) & 1ULL)) { \
                if (l == 0) klist[kept] = (i); \
                unsigned long long _d = (_wi < 64) ? __shfl(p0, _wi) \
                                                   : __shfl(p1, _wi - 64); \
                reg0 |= p0; \
                reg1 |= p1; \
                curw |= _d; \
                ++kept; \
            } \
        } }

    if (!done && kept < POST_NMS) {
        if (!final_phase) {
            unsigned long long p[16][2], dw[16];
            #pragma unroll
            for (int k = 0; k < 16; ++k) { LOADROW_T(p[k][0], p[k][1], dw[k], row_begin + k) }
            for (int i = row_begin; i < row_end && kept < POST_NMS; i += 16) {
                #pragma unroll
                for (int k = 0; k < 16; ++k) {
                    STEP_T(i + k, p[k][0], p[k][1], dw[k])
                    LOADROW_T(p[k][0], p[k][1], dw[k], i + 16 + k)
                }
            }
        } else {
            unsigned long long p[16][2];
            #pragma unroll
            for (int k = 0; k < 16; ++k) { LOADROW(p[k][0], p[k][1], row_begin + k) }
            for (int i = row_begin; i < row_end && kept < POST_NMS; i += 16) {
                #pragma unroll
                for (int k = 0; k < 16; ++k) {
                    STEP(i + k, p[k][0], p[k][1])
                    LOADROW(p[k][0], p[k][1], i + 16 + k)
                }
            }
        }
    }
    __syncthreads();

    if (!final_phase) {
        if (l == 0) { s_meta[0] = kept; s_meta[1] = (kept >= POST_NMS) ? 1 : 0; }
        s_supp[l] = reg0;
        if (l < RT_TILES - 64) s_supp[64 + l] = reg1;
        for (int k = l; k < POST_NMS; k += 64) s_klist[k] = klist[k];
    } else {
        for (int k = l; k < POST_NMS; k += 64) {
            size_t o = ((size_t)b * POST_NMS + k) * 5;
            float x1 = 0.f, y1 = 0.f, x2 = 0.f, y2 = 0.f;
            if (k < kept) {
                int idx = klist[k];
                const float4 v = *(const float4*)(boxes + ((size_t)b * PRE_NMS + idx) * 4);
                x1 = v.x; y1 = v.y; x2 = v.z; y2 = v.w;
            }
            out[o + 0] = (float)b;
            out[o + 1] = x1; out[o + 2] = y1; out[o + 3] = x2; out[o + 4] = y2;
        }
    }
#undef LOADROW_T
#undef STEP_T
#undef LOADROW
#undef STEP
}

// Fallback NMS (used only if ws_size is too small for the bitmask).
__global__ __launch_bounds__(1024) void k_nms_out(
    const float* __restrict__ boxes, float* __restrict__ out)
{
    __shared__ float bx1[PRE_NMS], by1[PRE_NMS], bx2[PRE_NMS], by2[PRE_NMS], bar[PRE_NMS];
    __shared__ unsigned rem[(PRE_NMS + 31) / 32];
    __shared__ int kept_idx[POST_NMS];

    int b = blockIdx.x;
    int t = threadIdx.x;

    for (int p = t; p < PRE_NMS; p += 1024) {
        size_t o = ((size_t)b * PRE_NMS + p) * 4;
        float x1 = boxes[o], y1 = boxes[o + 1], x2 = boxes[o + 2], y2 = boxes[o + 3];
        bx1[p] = x1; by1[p] = y1; bx2[p] = x2; by2[p] = y2;
        bar[p] = __fmul_rn(__fadd_rn(__fsub_rn(x2, x1), 1.0f),
                           __fadd_rn(__fsub_rn(y2, y1), 1.0f));
    }
    for (int p = t; p < (PRE_NMS + 31) / 32; p += 1024) rem[p] = 0u;
    __syncthreads();

    int kept = 0;
    for (int i = 0; i < PRE_NMS && kept < POST_NMS; ++i) {
        if (rem[i >> 5] & (1u << (i & 31))) continue;
        if (t == 0) kept_idx[kept] = i;
        float xi1 = bx1[i], yi1 = by1[i], xi2 = bx2[i], yi2 = by2[i], ai = bar[i];
        for (int j = i + 1 + t; j < PRE_NMS; j += 1024) {
            float xx1 = fmaxf(xi1, bx1[j]);
            float yy1 = fmaxf(yi1, by1[j]);
            float xx2 = fminf(xi2, bx2[j]);
            float yy2 = fminf(yi2, by2[j]);
            float iw = fmaxf(0.0f, __fadd_rn(__fsub_rn(xx2, xx1), 1.0f));
            float ih = fmaxf(0.0f, __fadd_rn(__fsub_rn(yy2, yy1), 1.0f));
            float inter = __fmul_rn(iw, ih);
            if (inter > 0.0f) {
                float uni = __fsub_rn(__fadd_rn(ai, bar[j]), inter);
                float iou = __fdiv_rn(inter, uni);
                if (iou > NMS_THRESH_F) atomicOr(&rem[j >> 5], 1u << (j & 31));
            }
        }
        ++kept;
        __syncthreads();
    }

    for (int k = t; k < POST_NMS; k += 1024) {
        size_t o = ((size_t)b * POST_NMS + k) * 5;
        out[o] = (float)b;
        if (k < kept) {
            int ii = kept_idx[k];
            out[o + 1] = bx1[ii]; out[o + 2] = by1[ii];
            out[o + 3] = bx2[ii]; out[o + 4] = by2[ii];
        } else {
            out[o + 1] = 0.0f; out[o + 2] = 0.0f; out[o + 3] = 0.0f; out[o + 4] = 0.0f;
        }
    }
}

extern "C" void kernel_launch(void* const* d_in, const int* in_sizes, int n_in,
                              void* d_out, int out_size, void* d_ws, size_t ws_size,
                              hipStream_t stream)
{
    const float* scores  = (const float*)d_in[0];
    const float* deltas  = (const float*)d_in[1];
    const float* im_info = (const float*)d_in[2];
    const float* anchors = (const float*)d_in[3];
    float* out = (float*)d_out;
    char* ws = (char*)d_ws;

    unsigned* keys             = (unsigned*)(ws + OFF_KEYS);
    unsigned* phist            = (unsigned*)(ws + OFF_PHIST);
    unsigned long long* tmask  = (unsigned long long*)(ws + OFF_TMASK);
    float* boxes               = (float*)(ws + OFF_BOXES);
    unsigned* bbro             = (unsigned*)(ws + OFF_BBRO);
    unsigned* bbmut            = (unsigned*)(ws + OFF_BBMUT);
    unsigned* thresh           = (unsigned*)(ws + OFF_CNT);
    unsigned* cnt              = thresh + 8;
    unsigned long long* seg    = (unsigned long long*)(ws + OFF_SEG);
    unsigned* ridx             = (unsigned*)(ws + OFF_RIDX);
    char* state                = (char*)(ws + OFF_STATE);
    unsigned long long* diagw  = (unsigned long long*)(ws + OFF_DIAG);
    unsigned long long* mask   = (unsigned long long*)(ws + OFF_MASK);

    int total = B_NUM * N_ANCH;
    int blk = 256;
    k_decode<<<(total + blk - 1) / blk, blk, 0, stream>>>(
        scores, deltas, im_info, anchors, keys);
    k_hist_part<<<B_NUM * 4, 1024, 0, stream>>>(keys, phist);
    k_thresh2<<<B_NUM, 1024, 0, stream>>>(phist, bbro, bbmut, thresh, cnt);
    k_scatter<<<(total + blk - 1) / blk, blk, 0, stream>>>(
        keys, thresh, bbmut, seg);
    k_rank<<<B_NUM * 32, 256, 0, stream>>>(seg, cnt, bbro, ridx);
    k_decode2<<<(B_NUM * PRE_NMS + blk - 1) / blk, blk, 0, stream>>>(
        ridx, deltas, im_info, anchors, boxes);

    if (ws_size >= (size_t)OFF_MASK + MASK_BYTES) {
        // phase A: rows 0..1023 only
        k_iou_mask<<<B_NUM * G_HEAD, 256, 0, stream>>>(
            boxes, mask, 0, G_HEAD, (const char*)0);
        // transpose head rows to row-major + extract diagonal words
        k_transpose<<<B_NUM * R_SPLIT, 1024, 0, stream>>>(mask, tmask, diagw);
        // scan p1: row-major scan, shuffle-free kept-row updates
        k_nms_scan_part<<<B_NUM, 64, 0, stream>>>(
            mask, tmask, diagw, boxes, out, state, 0, ROWS_SPLIT, 0);
        // tail: rows >= 1024, skipped per batch when done
        k_iou_mask<<<B_NUM * G_TAIL, 256, 0, stream>>>(
            boxes, mask, R_SPLIT, G_TAIL, (const char*)state);
        // scan p2: finish (or just write output if already done)
        k_nms_scan_part<<<B_NUM, 64, 0, stream>>>(
            mask, tmask, diagw, boxes, out, state, ROWS_SPLIT, PRE_NMS, 1);
    } else {
        k_nms_out<<<B_NUM, 1024, 0, stream>>>(boxes, out);
    }
}

// Round 29
// 154.094 us; speedup vs baseline: 1.1375x; 1.0884x over previous
//
#include <hip/hip_runtime.h>
#include <stdint.h>

#define FEAT_STRIDE_I 16
#define A_NUM 9
#define HH 128
#define WW 128
#define NPIX (HH * WW)            // 16384
#define N_ANCH (NPIX * A_NUM)     // 147456
#define B_NUM 8
#define PRE_NMS 6000
#define POST_NMS 300
#define NMS_THRESH_F 0.7f
#define MIN_SIZE_F 16.0f
#define NEG_INF_F -1e30f

#define NBS 16384                  // 14-bit bins (key>>18)
#define SWS(i) ((i) + ((i) >> 5))  // LDS swizzle
// cache-line spread for the mutable bin counters (round 24: -45us on scatter)
#define SWB(bin) ((((bin) & 1023) << 4) | ((bin) >> 10))
#define SEGL 8192                  // candidate segment cap (cnt ~6700 max)
#define QKEYS (N_ANCH / 4)         // 36864 keys per hist part

#define RT_TILES 94                // ceil(6000/64)
#define GT_TILES 600               // sum_R ceil((94-R)/8): 8-column groups
#define BQWORDS (RT_TILES * RT_TILES * 64)   // 565,504 qwords per batch

// truncated-IoU split: phase A computes row-tiles R < R_SPLIT (rows 0..1023);
// the tail (R >= R_SPLIT) is skipped per batch when the scan already kept 300.
#define R_SPLIT 16
#define ROWS_SPLIT (R_SPLIT * 64)  // 1024
#define G_HEAD 180                 // sum_{R=0..15} (101-R)>>3
#define G_TAIL (GT_TILES - G_HEAD) // 420
#define STATE_STRIDE 2048          // per-batch scan state (kept,done,supp,klist)
#define TMQ (ROWS_SPLIT * RT_TILES)            // 96,256 qwords per batch

// ---- workspace layout (bytes) ----
// KEYS and PHIST are dead by the time k_transpose runs; the row-major head
// mask (TMASK, 6,160,384 B) overlays them — no extra ws needed.
#define OFF_KEYS    0u             // 8*147456*4 = 4,718,592
#define OFF_PHIST   4718592u       // 8*4*16384*4 = 2,097,152 -> ends 6,815,744
#define OFF_TMASK   0u             // 8*96256*8 = 6,160,384 (overlay, late-use)
#define OFF_BOXES   6815744u       // 8*6000*4*4 = 768,000
#define OFF_BBRO    7583744u       // 8*16384*4 = 524,288 (read-only binbase)
#define OFF_BBMUT   8108032u       // 524,288 (scatter slot counters, swizzled)
#define OFF_CNT     8632320u       // thresh[8] + cnt[8] (512 B)
#define OFF_SEG     8632832u       // 8*8192*8 = 524,288
#define OFF_RIDX    9157120u       // 8*6000*4 = 192,000
#define OFF_STATE   9349120u       // 8*2048 = 16,384
#define OFF_DIAG    9365504u       // 8*1024*8 = 65,536 (diagonal words)
#define OFF_MASK    9431040u       // 36,192,256 -> end 45,623,296
#define MASK_BYTES ((size_t)B_NUM * BQWORDS * 8)

__device__ __forceinline__ unsigned sortable_f32(float f) {
    unsigned u = __float_as_uint(f);
    return (u & 0x80000000u) ? ~u : (u | 0x80000000u);
}

// Decode one anchor's box exactly in the reference's op order.
__device__ __forceinline__ void decode_box(
    int b, int idx,
    const float* __restrict__ deltas, const float* __restrict__ im_info,
    const float* __restrict__ anchors,
    float& x1, float& y1, float& x2, float& y2, bool& valid)
{
    int a   = idx % A_NUM;
    int pix = idx / A_NUM;
    int w   = pix & (WW - 1);
    int h   = pix >> 7;

    float a0 = anchors[a * 4 + 0];
    float a1 = anchors[a * 4 + 1];
    float a2 = anchors[a * 4 + 2];
    float a3 = anchors[a * 4 + 3];

    float aw = __fadd_rn(__fsub_rn(a2, a0), 1.0f);
    float ah = __fadd_rn(__fsub_rn(a3, a1), 1.0f);
    float sx = (float)(w * FEAT_STRIDE_I);
    float sy = (float)(h * FEAT_STRIDE_I);
    float acx = __fadd_rn(__fadd_rn(sx, a0), __fmul_rn(0.5f, aw));
    float acy = __fadd_rn(__fadd_rn(sy, a1), __fmul_rn(0.5f, ah));

    size_t base = ((size_t)b * 36 + 4 * a) * NPIX + pix;
    float dx = deltas[base];
    float dy = deltas[base + NPIX];
    float dw = deltas[base + 2 * (size_t)NPIX];
    float dh = deltas[base + 3 * (size_t)NPIX];

    float pcx = __fadd_rn(__fmul_rn(dx, aw), acx);
    float pcy = __fadd_rn(__fmul_rn(dy, ah), acy);
    float pw  = __fmul_rn(expf(dw), aw);
    float ph  = __fmul_rn(expf(dh), ah);

    float hx = __fmul_rn(0.5f, pw);
    float hy = __fmul_rn(0.5f, ph);
    x1 = __fsub_rn(pcx, hx);
    y1 = __fsub_rn(pcy, hy);
    x2 = __fadd_rn(pcx, hx);
    y2 = __fadd_rn(pcy, hy);

    float im_h = im_info[b * 3 + 0];
    float im_w = im_info[b * 3 + 1];
    float sc   = im_info[b * 3 + 2];
    float wmax = __fsub_rn(im_w, 1.0f);
    float hmax = __fsub_rn(im_h, 1.0f);

    x1 = fminf(fmaxf(x1, 0.0f), wmax);
    y1 = fminf(fmaxf(y1, 0.0f), hmax);
    x2 = fminf(fmaxf(x2, 0.0f), wmax);
    y2 = fminf(fmaxf(y2, 0.0f), hmax);

    float min_sz = __fmul_rn(MIN_SIZE_F, sc);
    valid = (__fadd_rn(__fsub_rn(x2, x1), 1.0f) >= min_sz) &&
            (__fadd_rn(__fsub_rn(y2, y1), 1.0f) >= min_sz);
}

// K1: decode + masked score -> sortable key. Pure streaming, no atomics.
__global__ void k_decode(
    const float* __restrict__ scores, const float* __restrict__ deltas,
    const float* __restrict__ im_info, const float* __restrict__ anchors,
    unsigned* __restrict__ keys)
{
    int gt = blockIdx.x * blockDim.x + threadIdx.x;
    if (gt >= B_NUM * N_ANCH) return;
    int pix  = gt & (NPIX - 1);
    int rest = gt >> 14;
    int a = rest % A_NUM;
    int b = rest / A_NUM;
    int idx = pix * A_NUM + a;

    float x1, y1, x2, y2; bool valid;
    decode_box(b, idx, deltas, im_info, anchors, x1, y1, x2, y2, valid);

    float s = scores[((size_t)b * 18 + 9 + a) * NPIX + pix];
    if (!valid) s = NEG_INF_F;
    keys[gt] = sortable_f32(s);
}

// K2: partial histograms — 4 blocks per batch, each hists one quarter of
// the keys in a private LDS 16384-bin histogram (staged uint4 loads).
__global__ __launch_bounds__(1024) void k_hist_part(
    const unsigned* __restrict__ keys, unsigned* __restrict__ phist)
{
    __shared__ unsigned h[SWS(NBS - 1) + 2];   // 16896 words = 67.6 KB
    int b = blockIdx.x >> 2;
    int p = blockIdx.x & 3;
    int t = threadIdx.x;

    for (int i = t; i < SWS(NBS - 1) + 2; i += 1024) h[i] = 0u;
    __syncthreads();

    const uint4* kb4 = (const uint4*)(keys + (size_t)b * N_ANCH + p * QKEYS);
    uint4 v[9];
    #pragma unroll
    for (int k = 0; k < 9; ++k) v[k] = kb4[t + 1024 * k];
    #pragma unroll
    for (int k = 0; k < 9; ++k) {
        atomicAdd(&h[SWS(v[k].x >> 18)], 1u);
        atomicAdd(&h[SWS(v[k].y >> 18)], 1u);
        atomicAdd(&h[SWS(v[k].z >> 18)], 1u);
        atomicAdd(&h[SWS(v[k].w >> 18)], 1u);
    }
    __syncthreads();

    unsigned* ph = phist + (size_t)blockIdx.x * NBS;
    for (int i = t; i < NBS; i += 1024) ph[i] = h[SWS(i)];
}

// K3: per batch — sum 4 partials, suffix-scan 16384 bins, find threshold T.
// bbro linear (read by k_rank); bbmut written SWB-swizzled (scatter atomics).
__global__ __launch_bounds__(1024) void k_thresh2(
    const unsigned* __restrict__ phist, unsigned* __restrict__ bbro,
    unsigned* __restrict__ bbmut, unsigned* __restrict__ thresh,
    unsigned* __restrict__ cnt)
{
    __shared__ unsigned h[SWS(NBS - 1) + 2];
    __shared__ unsigned csum[1024];
    __shared__ unsigned sT;

    int b = blockIdx.x;
    int t = threadIdx.x;
    if (t == 0) sT = 0;

    const unsigned* ph = phist + (size_t)b * 4 * NBS;
    for (int i = t; i < NBS; i += 1024) {
        unsigned s0 = ph[i];
        unsigned s1 = ph[NBS + i];
        unsigned s2 = ph[2 * NBS + i];
        unsigned s3 = ph[3 * NBS + i];
        h[SWS(i)] = s0 + s1 + s2 + s3;
    }
    __syncthreads();

    int base = t * 16;
    unsigned s = 0;
    for (int u = 0; u < 16; ++u) s += h[SWS(base + u)];
    csum[t] = s;
    __syncthreads();
    for (int off = 1; off < 1024; off <<= 1) {
        unsigned v = (t + off < 1024) ? csum[t + off] : 0u;
        __syncthreads();
        csum[t] += v;
        __syncthreads();
    }
    unsigned before = csum[t] - s;

    unsigned acc = before;
    for (int bin = base + 15; bin >= base; --bin) {
        unsigned hh = h[SWS(bin)];
        if (acc + hh >= PRE_NMS) { atomicMax(&sT, (unsigned)bin); break; }
        acc += hh;
    }
    __syncthreads();
    unsigned T = sT;

    acc = before;
    for (int bin = base + 15; bin >= base; --bin) {
        unsigned hh = h[SWS(bin)];
        if ((unsigned)bin == T) cnt[b] = acc + hh;
        h[SWS(bin)] = acc;
        acc += hh;
    }
    if (t == 0) thresh[b] = T;
    __syncthreads();

    unsigned* r = bbro + (size_t)b * NBS;
    unsigned* m = bbmut + (size_t)b * NBS;
    for (int i = t; i < NBS; i += 1024) {
        unsigned v = h[SWS(i)];
        r[i] = v;
        m[SWB(i)] = v;
    }
}

// K4: bin-segmented scatter — slot allocated by atomicAdd on the SWIZZLED
// mutable binbase copy.
__global__ void k_scatter(
    const unsigned* __restrict__ keys, const unsigned* __restrict__ thresh,
    unsigned* __restrict__ bbmut, unsigned long long* __restrict__ seg)
{
    int gt = blockIdx.x * blockDim.x + threadIdx.x;
    int pix  = gt & (NPIX - 1);
    int rest = gt >> 14;
    int a = rest % A_NUM;
    int b = rest / A_NUM;

    unsigned key = keys[gt];
    unsigned bin = key >> 18;
    if (bin >= thresh[b]) {
        unsigned pos = atomicAdd(&bbmut[(size_t)b * NBS + SWB(bin)], 1u);
        if (pos < SEGL) {
            unsigned idx = (unsigned)(pix * A_NUM + a);
            seg[(size_t)b * SEGL + pos] =
                ((unsigned long long)key << 32) | (unsigned long long)(0xFFFFFFFFu - idx);
        }
    }
}

// K5a: many-block counting rank (32 blocks x 256 thr per batch, all CUs).
__global__ __launch_bounds__(256) void k_rank(
    const unsigned long long* __restrict__ seg, const unsigned* __restrict__ cnt,
    const unsigned* __restrict__ bbro, unsigned* __restrict__ ridx)
{
    int b = blockIdx.x >> 5;
    int p = ((blockIdx.x & 31) << 8) + threadIdx.x;
    unsigned n = cnt[b];
    if (n > SEGL) n = SEGL;
    if (p >= (int)n) return;

    const unsigned long long* S = seg + (size_t)b * SEGL;
    unsigned long long key = S[p];
    unsigned bin = (unsigned)(key >> 50);
    const unsigned* bb = bbro + (size_t)b * NBS;
    unsigned base = bb[bin];
    unsigned end = (bin > 0) ? bb[bin - 1] : n;
    if (end > n) end = n;

    unsigned rank = base;
    unsigned q = base;
    for (; q + 8 <= end; q += 8) {
        unsigned long long v0 = S[q + 0], v1 = S[q + 1];
        unsigned long long v2 = S[q + 2], v3 = S[q + 3];
        unsigned long long v4 = S[q + 4], v5 = S[q + 5];
        unsigned long long v6 = S[q + 6], v7 = S[q + 7];
        rank += (unsigned)(v0 > key) + (unsigned)(v1 > key)
              + (unsigned)(v2 > key) + (unsigned)(v3 > key)
              + (unsigned)(v4 > key) + (unsigned)(v5 > key)
              + (unsigned)(v6 > key) + (unsigned)(v7 > key);
    }
    for (; q < end; ++q) rank += (unsigned)(S[q] > key);

    if (rank < PRE_NMS)
        ridx[(size_t)b * PRE_NMS + rank] = 0xFFFFFFFFu - (unsigned)(key & 0xFFFFFFFFull);
}

// K5b: decode one box per output rank across all CUs.
__global__ void k_decode2(
    const unsigned* __restrict__ ridx,
    const float* __restrict__ deltas, const float* __restrict__ im_info,
    const float* __restrict__ anchors, float* __restrict__ boxes)
{
    int gt = blockIdx.x * blockDim.x + threadIdx.x;
    if (gt >= B_NUM * PRE_NMS) return;
    int b = gt / PRE_NMS;
    int idx = (int)ridx[gt];
    float x1, y1, x2, y2; bool v;
    decode_box(b, idx, deltas, im_info, anchors, x1, y1, x2, y2, v);
    *(float4*)(boxes + (size_t)gt * 4) = make_float4(x1, y1, x2, y2);
}

// One row of a 64x64 suppression block (exact ref op order; div only in the
// proven +-6e-7*uni band — validated absmax=0 since round 6).
__device__ __forceinline__ unsigned long long iou_row(
    float4 bi, float ia, float jx1, float jy1, float jx2, float jy2, float ja)
{
    float xx1 = fmaxf(bi.x, jx1);
    float yy1 = fmaxf(bi.y, jy1);
    float xx2 = fminf(bi.z, jx2);
    float yy2 = fminf(bi.w, jy2);
    float iw = fmaxf(0.0f, __fadd_rn(__fsub_rn(xx2, xx1), 1.0f));
    float ih = fmaxf(0.0f, __fadd_rn(__fsub_rn(yy2, yy1), 1.0f));
    float inter = __fmul_rn(iw, ih);
    float uni = __fsub_rn(__fadd_rn(ia, ja), inter);
    float diff = __fsub_rn(inter, __fmul_rn(NMS_THRESH_F, uni));
    unsigned long long sup = __ballot(diff > 0.0f);
    unsigned long long band = __ballot(fabsf(diff) <= __fmul_rn(6e-7f, uni));
    if (band) {
        unsigned long long supd = __ballot(__fdiv_rn(inter, uni) > NMS_THRESH_F);
        sup = (sup & ~band) | (supd & band);
    }
    return sup;
}

// K6: IoU suppression bitmask for row-tiles R in [Rstart, ...), ngroups
// 8-column groups per batch. statep!=null: skip batch if its scan already
// finished (done flag). Layout mask[b][R][C][64].
__global__ __launch_bounds__(256) void k_iou_mask(
    const float* __restrict__ boxes, unsigned long long* __restrict__ mask,
    int Rstart, int ngroups, const char* __restrict__ statep)
{
    int bid = blockIdx.x;
    int b = bid / ngroups;
    int g = bid - b * ngroups;
    if (statep && ((const int*)(statep + (size_t)b * STATE_STRIDE))[1]) return;

    int R = Rstart;
    while (g >= ((RT_TILES - R + 7) >> 3)) { g -= (RT_TILES - R + 7) >> 3; ++R; }

    int wave = threadIdx.x >> 6;
    int lane = threadIdx.x & 63;
    const float* Bb = boxes + (size_t)b * PRE_NMS * 4;

    __shared__ float4 rb4[64];
    __shared__ float rba[64];
    if (threadIdx.x < 64) {
        int il = R * 64 + threadIdx.x;
        float4 rv = make_float4(0.f, 0.f, -1.f, -1.f);
        if (il < PRE_NMS) rv = *(const float4*)(Bb + 4 * (size_t)il);
        rb4[threadIdx.x] = rv;
        rba[threadIdx.x] = __fmul_rn(__fadd_rn(__fsub_rn(rv.z, rv.x), 1.0f),
                                     __fadd_rn(__fsub_rn(rv.w, rv.y), 1.0f));
    }
    __syncthreads();

    int C1 = R + g * 8 + wave * 2;
    int C2 = C1 + 1;
    if (C1 >= RT_TILES) return;   // tail waves idle (no barriers below)

    float j1x1 = 0.f, j1y1 = 0.f, j1x2 = -1.f, j1y2 = -1.f;
    float j2x1 = 0.f, j2y1 = 0.f, j2x2 = -1.f, j2y2 = -1.f;
    int j1 = C1 * 64 + lane;
    int j2 = C2 * 64 + lane;
    if (j1 < PRE_NMS) {
        float4 v = *(const float4*)(Bb + 4 * (size_t)j1);
        j1x1 = v.x; j1y1 = v.y; j1x2 = v.z; j1y2 = v.w;
    }
    if (C2 < RT_TILES && j2 < PRE_NMS) {
        float4 v = *(const float4*)(Bb + 4 * (size_t)j2);
        j2x1 = v.x; j2y1 = v.y; j2x2 = v.z; j2y2 = v.w;
    }
    float j1a = __fmul_rn(__fadd_rn(__fsub_rn(j1x2, j1x1), 1.0f),
                          __fadd_rn(__fsub_rn(j1y2, j1y1), 1.0f));
    float j2a = __fmul_rn(__fadd_rn(__fsub_rn(j2x2, j2x1), 1.0f),
                          __fadd_rn(__fsub_rn(j2y2, j2y1), 1.0f));

    unsigned long long w1 = 0ULL, w2 = 0ULL;
    if (C1 == R) {   // diagonal tile
        #pragma unroll 4
        for (int ri = 0; ri < 64; ++ri) {
            float4 bi = rb4[ri];
            float ia = rba[ri];
            unsigned long long s1 = iou_row(bi, ia, j1x1, j1y1, j1x2, j1y2, j1a)
                                    & (0xFFFFFFFFFFFFFFFEull << ri);
            unsigned long long s2 = iou_row(bi, ia, j2x1, j2y1, j2x2, j2y2, j2a);
            w1 = (lane == ri) ? s1 : w1;
            w2 = (lane == ri) ? s2 : w2;
        }
    } else {
        #pragma unroll 4
        for (int ri = 0; ri < 64; ++ri) {
            float4 bi = rb4[ri];
            float ia = rba[ri];
            unsigned long long s1 = iou_row(bi, ia, j1x1, j1y1, j1x2, j1y2, j1a);
            unsigned long long s2 = iou_row(bi, ia, j2x1, j2y1, j2x2, j2y2, j2a);
            w1 = (lane == ri) ? s1 : w1;
            w2 = (lane == ri) ? s2 : w2;
        }
    }

    unsigned long long* Mb = mask + (size_t)b * BQWORDS;
    Mb[(size_t)(R * RT_TILES + C1) * 64 + lane] = w1;
    if (C2 < RT_TILES)
        Mb[(size_t)(R * RT_TILES + C2) * 64 + lane] = w2;
}

// K6b: transpose head mask [R][C][64] -> row-major tmask[i][C] for rows
// < ROWS_SPLIT; also emit diagw[i] = tmask[i][i>>6] (the row's own-tile
// suppression word) so the scan's kept-row update needs no cross-lane
// shuffle (round-28: -4us).
__global__ __launch_bounds__(1024) void k_transpose(
    const unsigned long long* __restrict__ mask,
    unsigned long long* __restrict__ tmask,
    unsigned long long* __restrict__ diagw)
{
    __shared__ unsigned long long tile[64 * RT_TILES];   // 48,128 B
    int b = blockIdx.x >> 4;
    int R = blockIdx.x & 15;
    int t = threadIdx.x;
    const unsigned long long* Mb =
        mask + (size_t)b * BQWORDS + (size_t)R * RT_TILES * 64;
    for (int idx = t; idx < RT_TILES * 64; idx += 1024) {
        int C = idx >> 6, r = idx & 63;
        tile[r * RT_TILES + C] = Mb[(size_t)C * 64 + r];
    }
    __syncthreads();
    unsigned long long* Tb =
        tmask + (size_t)b * TMQ + (size_t)R * 64 * RT_TILES;
    for (int idx = t; idx < 64 * RT_TILES; idx += 1024)
        Tb[idx] = tile[idx];
    if (t < 64)
        diagw[(size_t)b * ROWS_SPLIT + R * 64 + t] = tile[t * RT_TILES + R];
}

// K7: greedy scan, resumable. One wave/batch. Suppression state in
// registers (lane l owns words l, 64+l).
// p1 (final_phase==0): row-major scan, round-29 BRANCHLESS step: the
// remaining 123cy/row was wave-level branch overhead (3 s_cbranch/row).
// Groups of 16 rows never straddle a 64-row tile, so the curw seed shuffle
// is hoisted to once per group; the per-row body is pure arithmetic
// (keep -> mask -> masked ORs -> kept+=keep) with only an exec-masked
// klist store. Semantics identical to the branchy version.
// p2 (final_phase==1): old per-row path on the strided mask layout.
__global__ __launch_bounds__(64) void k_nms_scan_part(
    const unsigned long long* __restrict__ mask,
    const unsigned long long* __restrict__ tmask,
    const unsigned long long* __restrict__ diagw,
    const float* __restrict__ boxes, float* __restrict__ out,
    char* __restrict__ statep, int row_begin, int row_end, int final_phase)
{
    const int b = blockIdx.x;
    const int l = threadIdx.x;
    char* st = statep + (size_t)b * STATE_STRIDE;
    int* s_meta = (int*)st;
    unsigned long long* s_supp = (unsigned long long*)(st + 16);
    int* s_klist = (int*)(st + 768);

    __shared__ int klist[POST_NMS];
    unsigned long long reg0, reg1;   // suppression words l and 64+l
    int kept, done;

    if (row_begin == 0) {
        reg0 = 0ULL; reg1 = 0ULL;
        kept = 0; done = 0;
    } else {
        kept = s_meta[0];
        done = s_meta[1];
        reg0 = s_supp[l];
        reg1 = (l < RT_TILES - 64) ? s_supp[64 + l] : 0ULL;
        for (int k = l; k < POST_NMS; k += 64) klist[k] = s_klist[k];
    }
    __syncthreads();

    const unsigned long long* __restrict__ M = mask + (size_t)b * BQWORDS;
    const unsigned long long* __restrict__ TM = tmask + (size_t)b * TMQ;
    const unsigned long long* __restrict__ DW = diagw + (size_t)b * ROWS_SPLIT;
    unsigned long long curw = 0; int curwi = -1;

#define LOADROW_T(p0, p1, dwv, i) { \
        int _i = ((i) < ROWS_SPLIT) ? (i) : (ROWS_SPLIT - 1); \
        const unsigned long long* _r = TM + (size_t)_i * RT_TILES; \
        p0 = _r[l]; \
        p1 = (l < RT_TILES - 64) ? _r[64 + l] : 0ULL; \
        dwv = DW[_i]; }

#define LOADROW(p0, p1, i) { \
        int _i = ((i) < PRE_NMS) ? (i) : (PRE_NMS - 1); \
        int _R = _i >> 6; \
        const unsigned long long* _r = M + (size_t)(_R * RT_TILES) * 64 + (_i & 63); \
        p0 = 0ULL; p1 = 0ULL; \
        if (l >= _R) p0 = _r[l * 64]; \
        if (l < RT_TILES - 64 && 64 + l >= _R) p1 = _r[(64 + l) * 64]; }

#define STEP(i, p0, p1) { \
        if (kept < POST_NMS) { \
            int _wi = (i) >> 6; \
            if (_wi != curwi) { \
                curw = (_wi < 64) ? __shfl(reg0, _wi) : __shfl(reg1, _wi - 64); \
                curwi = _wi; \
            } \
            if (!((curw >> ((i) & 63)) & 1ULL)) { \
                if (l == 0) klist[kept] = (i); \
                unsigned long long _d = (_wi < 64) ? __shfl(p0, _wi) \
                                                   : __shfl(p1, _wi - 64); \
                reg0 |= p0; \
                reg1 |= p1; \
                curw |= _d; \
                ++kept; \
            } \
        } }

    if (!done && kept < POST_NMS) {
        if (!final_phase) {
            unsigned long long p[16][2], dw[16];
            #pragma unroll
            for (int k = 0; k < 16; ++k) { LOADROW_T(p[k][0], p[k][1], dw[k], row_begin + k) }
            for (int i = row_begin; i < row_end && kept < POST_NMS; i += 16) {
                // groups of 16 never straddle a 64-row tile: hoist seed
                int wi = i >> 6;
                if (wi != curwi) { curw = __shfl(reg0, wi); curwi = wi; }
                int ib = i & 63;
                #pragma unroll
                for (int k = 0; k < 16; ++k) {
                    // branchless step
                    int keep = (int)((~(curw >> (ib + k))) & 1ULL) &
                               ((kept < POST_NMS) ? 1 : 0);
                    unsigned long long m = 0ULL - (unsigned long long)keep;
                    if ((l == 0) & keep) klist[kept] = i + k;
                    reg0 |= p[k][0] & m;
                    reg1 |= p[k][1] & m;
                    curw |= dw[k] & m;
                    kept += keep;
                    LOADROW_T(p[k][0], p[k][1], dw[k], i + 16 + k)
                }
            }
        } else {
            unsigned long long p[16][2];
            #pragma unroll
            for (int k = 0; k < 16; ++k) { LOADROW(p[k][0], p[k][1], row_begin + k) }
            for (int i = row_begin; i < row_end && kept < POST_NMS; i += 16) {
                #pragma unroll
                for (int k = 0; k < 16; ++k) {
                    STEP(i + k, p[k][0], p[k][1])
                    LOADROW(p[k][0], p[k][1], i + 16 + k)
                }
            }
        }
    }
    __syncthreads();

    if (!final_phase) {
        if (l == 0) { s_meta[0] = kept; s_meta[1] = (kept >= POST_NMS) ? 1 : 0; }
        s_supp[l] = reg0;
        if (l < RT_TILES - 64) s_supp[64 + l] = reg1;
        for (int k = l; k < POST_NMS; k += 64) s_klist[k] = klist[k];
    } else {
        for (int k = l; k < POST_NMS; k += 64) {
            size_t o = ((size_t)b * POST_NMS + k) * 5;
            float x1 = 0.f, y1 = 0.f, x2 = 0.f, y2 = 0.f;
            if (k < kept) {
                int idx = klist[k];
                const float4 v = *(const float4*)(boxes + ((size_t)b * PRE_NMS + idx) * 4);
                x1 = v.x; y1 = v.y; x2 = v.z; y2 = v.w;
            }
            out[o + 0] = (float)b;
            out[o + 1] = x1; out[o + 2] = y1; out[o + 3] = x2; out[o + 4] = y2;
        }
    }
#undef LOADROW_T
#undef LOADROW
#undef STEP
}

// Fallback NMS (used only if ws_size is too small for the bitmask).
__global__ __launch_bounds__(1024) void k_nms_out(
    const float* __restrict__ boxes, float* __restrict__ out)
{
    __shared__ float bx1[PRE_NMS], by1[PRE_NMS], bx2[PRE_NMS], by2[PRE_NMS], bar[PRE_NMS];
    __shared__ unsigned rem[(PRE_NMS + 31) / 32];
    __shared__ int kept_idx[POST_NMS];

    int b = blockIdx.x;
    int t = threadIdx.x;

    for (int p = t; p < PRE_NMS; p += 1024) {
        size_t o = ((size_t)b * PRE_NMS + p) * 4;
        float x1 = boxes[o], y1 = boxes[o + 1], x2 = boxes[o + 2], y2 = boxes[o + 3];
        bx1[p] = x1; by1[p] = y1; bx2[p] = x2; by2[p] = y2;
        bar[p] = __fmul_rn(__fadd_rn(__fsub_rn(x2, x1), 1.0f),
                           __fadd_rn(__fsub_rn(y2, y1), 1.0f));
    }
    for (int p = t; p < (PRE_NMS + 31) / 32; p += 1024) rem[p] = 0u;
    __syncthreads();

    int kept = 0;
    for (int i = 0; i < PRE_NMS && kept < POST_NMS; ++i) {
        if (rem[i >> 5] & (1u << (i & 31))) continue;
        if (t == 0) kept_idx[kept] = i;
        float xi1 = bx1[i], yi1 = by1[i], xi2 = bx2[i], yi2 = by2[i], ai = bar[i];
        for (int j = i + 1 + t; j < PRE_NMS; j += 1024) {
            float xx1 = fmaxf(xi1, bx1[j]);
            float yy1 = fmaxf(yi1, by1[j]);
            float xx2 = fminf(xi2, bx2[j]);
            float yy2 = fminf(yi2, by2[j]);
            float iw = fmaxf(0.0f, __fadd_rn(__fsub_rn(xx2, xx1), 1.0f));
            float ih = fmaxf(0.0f, __fadd_rn(__fsub_rn(yy2, yy1), 1.0f));
            float inter = __fmul_rn(iw, ih);
            if (inter > 0.0f) {
                float uni = __fsub_rn(__fadd_rn(ai, bar[j]), inter);
                float iou = __fdiv_rn(inter, uni);
                if (iou > NMS_THRESH_F) atomicOr(&rem[j >> 5], 1u << (j & 31));
            }
        }
        ++kept;
        __syncthreads();
    }

    for (int k = t; k < POST_NMS; k += 1024) {
        size_t o = ((size_t)b * POST_NMS + k) * 5;
        out[o] = (float)b;
        if (k < kept) {
            int ii = kept_idx[k];
            out[o + 1] = bx1[ii]; out[o + 2] = by1[ii];
            out[o + 3] = bx2[ii]; out[o + 4] = by2[ii];
        } else {
            out[o + 1] = 0.0f; out[o + 2] = 0.0f; out[o + 3] = 0.0f; out[o + 4] = 0.0f;
        }
    }
}

extern "C" void kernel_launch(void* const* d_in, const int* in_sizes, int n_in,
                              void* d_out, int out_size, void* d_ws, size_t ws_size,
                              hipStream_t stream)
{
    const float* scores  = (const float*)d_in[0];
    const float* deltas  = (const float*)d_in[1];
    const float* im_info = (const float*)d_in[2];
    const float* anchors = (const float*)d_in[3];
    float* out = (float*)d_out;
    char* ws = (char*)d_ws;

    unsigned* keys             = (unsigned*)(ws + OFF_KEYS);
    unsigned* phist            = (unsigned*)(ws + OFF_PHIST);
    unsigned long long* tmask  = (unsigned long long*)(ws + OFF_TMASK);
    float* boxes               = (float*)(ws + OFF_BOXES);
    unsigned* bbro             = (unsigned*)(ws + OFF_BBRO);
    unsigned* bbmut            = (unsigned*)(ws + OFF_BBMUT);
    unsigned* thresh           = (unsigned*)(ws + OFF_CNT);
    unsigned* cnt              = thresh + 8;
    unsigned long long* seg    = (unsigned long long*)(ws + OFF_SEG);
    unsigned* ridx             = (unsigned*)(ws + OFF_RIDX);
    char* state                = (char*)(ws + OFF_STATE);
    unsigned long long* diagw  = (unsigned long long*)(ws + OFF_DIAG);
    unsigned long long* mask   = (unsigned long long*)(ws + OFF_MASK);

    int total = B_NUM * N_ANCH;
    int blk = 256;
    k_decode<<<(total + blk - 1) / blk, blk, 0, stream>>>(
        scores, deltas, im_info, anchors, keys);
    k_hist_part<<<B_NUM * 4, 1024, 0, stream>>>(keys, phist);
    k_thresh2<<<B_NUM, 1024, 0, stream>>>(phist, bbro, bbmut, thresh, cnt);
    k_scatter<<<(total + blk - 1) / blk, blk, 0, stream>>>(
        keys, thresh, bbmut, seg);
    k_rank<<<B_NUM * 32, 256, 0, stream>>>(seg, cnt, bbro, ridx);
    k_decode2<<<(B_NUM * PRE_NMS + blk - 1) / blk, blk, 0, stream>>>(
        ridx, deltas, im_info, anchors, boxes);

    if (ws_size >= (size_t)OFF_MASK + MASK_BYTES) {
        // phase A: rows 0..1023 only
        k_iou_mask<<<B_NUM * G_HEAD, 256, 0, stream>>>(
            boxes, mask, 0, G_HEAD, (const char*)0);
        // transpose head rows to row-major + extract diagonal words
        k_transpose<<<B_NUM * R_SPLIT, 1024, 0, stream>>>(mask, tmask, diagw);
        // scan p1: row-major scan, branchless steps
        k_nms_scan_part<<<B_NUM, 64, 0, stream>>>(
            mask, tmask, diagw, boxes, out, state, 0, ROWS_SPLIT, 0);
        // tail: rows >= 1024, skipped per batch when done
        k_iou_mask<<<B_NUM * G_TAIL, 256, 0, stream>>>(
            boxes, mask, R_SPLIT, G_TAIL, (const char*)state);
        // scan p2: finish (or just write output if already done)
        k_nms_scan_part<<<B_NUM, 64, 0, stream>>>(
            mask, tmask, diagw, boxes, out, state, ROWS_SPLIT, PRE_NMS, 1);
    } else {
        k_nms_out<<<B_NUM, 1024, 0, stream>>>(boxes, out);
    }
}

// Round 30
// 153.344 us; speedup vs baseline: 1.1430x; 1.0049x over previous
//
#include <hip/hip_runtime.h>
#include <stdint.h>

#define FEAT_STRIDE_I 16
#define A_NUM 9
#define HH 128
#define WW 128
#define NPIX (HH * WW)            // 16384
#define N_ANCH (NPIX * A_NUM)     // 147456
#define B_NUM 8
#define PRE_NMS 6000
#define POST_NMS 300
#define NMS_THRESH_F 0.7f
#define MIN_SIZE_F 16.0f
#define NEG_INF_F -1e30f

#define NBS 16384                  // 14-bit bins (key>>18)
#define SWS(i) ((i) + ((i) >> 5))  // LDS swizzle
// cache-line spread for the mutable bin counters (round 24: -45us on scatter)
#define SWB(bin) ((((bin) & 1023) << 4) | ((bin) >> 10))
#define SEGL 8192                  // candidate segment cap (cnt ~6700 max)
#define QKEYS (N_ANCH / 4)         // 36864 keys per hist part

#define RT_TILES 94                // ceil(6000/64)
#define GT_TILES 600               // sum_R ceil((94-R)/8): 8-column groups
#define BQWORDS (RT_TILES * RT_TILES * 64)   // 565,504 qwords per batch

// truncated-IoU split: phase A computes row-tiles R < R_SPLIT (rows 0..1023);
// the tail (R >= R_SPLIT) is skipped per batch when the scan already kept 300.
#define R_SPLIT 16
#define ROWS_SPLIT (R_SPLIT * 64)  // 1024
#define G_HEAD 180                 // sum_{R=0..15} (101-R)>>3
#define G_TAIL (GT_TILES - G_HEAD) // 420
#define STATE_STRIDE 2048          // per-batch scan state (kept,done,supp,klist)
#define TMQ (ROWS_SPLIT * RT_TILES)            // 96,256 qwords per batch

// ---- workspace layout (bytes) ----
// KEYS and PHIST are dead by the time k_transpose runs; the row-major head
// mask (TMASK, 6,160,384 B) overlays them — no extra ws needed. The scan's
// prefetch overruns tmask by <=16 rows (12KB) into the dead phist region
// (in-bounds; values never consumed).
#define OFF_KEYS    0u             // 8*147456*4 = 4,718,592
#define OFF_PHIST   4718592u       // 8*4*16384*4 = 2,097,152 -> ends 6,815,744
#define OFF_TMASK   0u             // 8*96256*8 = 6,160,384 (overlay, late-use)
#define OFF_BOXES   6815744u       // 8*6000*4*4 = 768,000
#define OFF_BBRO    7583744u       // 8*16384*4 = 524,288 (read-only binbase)
#define OFF_BBMUT   8108032u       // 524,288 (scatter slot counters, swizzled)
#define OFF_CNT     8632320u       // thresh[8] + cnt[8] (512 B)
#define OFF_SEG     8632832u       // 8*8192*8 = 524,288
#define OFF_RIDX    9157120u       // 8*6000*4 = 192,000
#define OFF_STATE   9349120u       // 8*2048 = 16,384
#define OFF_DIAG    9365504u       // 8*1024*8 = 65,536 (diagonal words)
#define OFF_MASK    9431040u       // 36,192,256 -> end 45,623,296
#define MASK_BYTES ((size_t)B_NUM * BQWORDS * 8)

__device__ __forceinline__ unsigned sortable_f32(float f) {
    unsigned u = __float_as_uint(f);
    return (u & 0x80000000u) ? ~u : (u | 0x80000000u);
}

// Decode one anchor's box exactly in the reference's op order.
__device__ __forceinline__ void decode_box(
    int b, int idx,
    const float* __restrict__ deltas, const float* __restrict__ im_info,
    const float* __restrict__ anchors,
    float& x1, float& y1, float& x2, float& y2, bool& valid)
{
    int a   = idx % A_NUM;
    int pix = idx / A_NUM;
    int w   = pix & (WW - 1);
    int h   = pix >> 7;

    float a0 = anchors[a * 4 + 0];
    float a1 = anchors[a * 4 + 1];
    float a2 = anchors[a * 4 + 2];
    float a3 = anchors[a * 4 + 3];

    float aw = __fadd_rn(__fsub_rn(a2, a0), 1.0f);
    float ah = __fadd_rn(__fsub_rn(a3, a1), 1.0f);
    float sx = (float)(w * FEAT_STRIDE_I);
    float sy = (float)(h * FEAT_STRIDE_I);
    float acx = __fadd_rn(__fadd_rn(sx, a0), __fmul_rn(0.5f, aw));
    float acy = __fadd_rn(__fadd_rn(sy, a1), __fmul_rn(0.5f, ah));

    size_t base = ((size_t)b * 36 + 4 * a) * NPIX + pix;
    float dx = deltas[base];
    float dy = deltas[base + NPIX];
    float dw = deltas[base + 2 * (size_t)NPIX];
    float dh = deltas[base + 3 * (size_t)NPIX];

    float pcx = __fadd_rn(__fmul_rn(dx, aw), acx);
    float pcy = __fadd_rn(__fmul_rn(dy, ah), acy);
    float pw  = __fmul_rn(expf(dw), aw);
    float ph  = __fmul_rn(expf(dh), ah);

    float hx = __fmul_rn(0.5f, pw);
    float hy = __fmul_rn(0.5f, ph);
    x1 = __fsub_rn(pcx, hx);
    y1 = __fsub_rn(pcy, hy);
    x2 = __fadd_rn(pcx, hx);
    y2 = __fadd_rn(pcy, hy);

    float im_h = im_info[b * 3 + 0];
    float im_w = im_info[b * 3 + 1];
    float sc   = im_info[b * 3 + 2];
    float wmax = __fsub_rn(im_w, 1.0f);
    float hmax = __fsub_rn(im_h, 1.0f);

    x1 = fminf(fmaxf(x1, 0.0f), wmax);
    y1 = fminf(fmaxf(y1, 0.0f), hmax);
    x2 = fminf(fmaxf(x2, 0.0f), wmax);
    y2 = fminf(fmaxf(y2, 0.0f), hmax);

    float min_sz = __fmul_rn(MIN_SIZE_F, sc);
    valid = (__fadd_rn(__fsub_rn(x2, x1), 1.0f) >= min_sz) &&
            (__fadd_rn(__fsub_rn(y2, y1), 1.0f) >= min_sz);
}

// K1: decode + masked score -> sortable key. Pure streaming, no atomics.
__global__ void k_decode(
    const float* __restrict__ scores, const float* __restrict__ deltas,
    const float* __restrict__ im_info, const float* __restrict__ anchors,
    unsigned* __restrict__ keys)
{
    int gt = blockIdx.x * blockDim.x + threadIdx.x;
    if (gt >= B_NUM * N_ANCH) return;
    int pix  = gt & (NPIX - 1);
    int rest = gt >> 14;
    int a = rest % A_NUM;
    int b = rest / A_NUM;
    int idx = pix * A_NUM + a;

    float x1, y1, x2, y2; bool valid;
    decode_box(b, idx, deltas, im_info, anchors, x1, y1, x2, y2, valid);

    float s = scores[((size_t)b * 18 + 9 + a) * NPIX + pix];
    if (!valid) s = NEG_INF_F;
    keys[gt] = sortable_f32(s);
}

// K2: partial histograms — 4 blocks per batch, each hists one quarter of
// the keys in a private LDS 16384-bin histogram (staged uint4 loads).
__global__ __launch_bounds__(1024) void k_hist_part(
    const unsigned* __restrict__ keys, unsigned* __restrict__ phist)
{
    __shared__ unsigned h[SWS(NBS - 1) + 2];   // 16896 words = 67.6 KB
    int b = blockIdx.x >> 2;
    int p = blockIdx.x & 3;
    int t = threadIdx.x;

    for (int i = t; i < SWS(NBS - 1) + 2; i += 1024) h[i] = 0u;
    __syncthreads();

    const uint4* kb4 = (const uint4*)(keys + (size_t)b * N_ANCH + p * QKEYS);
    uint4 v[9];
    #pragma unroll
    for (int k = 0; k < 9; ++k) v[k] = kb4[t + 1024 * k];
    #pragma unroll
    for (int k = 0; k < 9; ++k) {
        atomicAdd(&h[SWS(v[k].x >> 18)], 1u);
        atomicAdd(&h[SWS(v[k].y >> 18)], 1u);
        atomicAdd(&h[SWS(v[k].z >> 18)], 1u);
        atomicAdd(&h[SWS(v[k].w >> 18)], 1u);
    }
    __syncthreads();

    unsigned* ph = phist + (size_t)blockIdx.x * NBS;
    for (int i = t; i < NBS; i += 1024) ph[i] = h[SWS(i)];
}

// K3: per batch — sum 4 partials, suffix-scan 16384 bins, find threshold T.
// bbro linear (read by k_rank); bbmut written SWB-swizzled (scatter atomics).
__global__ __launch_bounds__(1024) void k_thresh2(
    const unsigned* __restrict__ phist, unsigned* __restrict__ bbro,
    unsigned* __restrict__ bbmut, unsigned* __restrict__ thresh,
    unsigned* __restrict__ cnt)
{
    __shared__ unsigned h[SWS(NBS - 1) + 2];
    __shared__ unsigned csum[1024];
    __shared__ unsigned sT;

    int b = blockIdx.x;
    int t = threadIdx.x;
    if (t == 0) sT = 0;

    const unsigned* ph = phist + (size_t)b * 4 * NBS;
    for (int i = t; i < NBS; i += 1024) {
        unsigned s0 = ph[i];
        unsigned s1 = ph[NBS + i];
        unsigned s2 = ph[2 * NBS + i];
        unsigned s3 = ph[3 * NBS + i];
        h[SWS(i)] = s0 + s1 + s2 + s3;
    }
    __syncthreads();

    int base = t * 16;
    unsigned s = 0;
    for (int u = 0; u < 16; ++u) s += h[SWS(base + u)];
    csum[t] = s;
    __syncthreads();
    for (int off = 1; off < 1024; off <<= 1) {
        unsigned v = (t + off < 1024) ? csum[t + off] : 0u;
        __syncthreads();
        csum[t] += v;
        __syncthreads();
    }
    unsigned before = csum[t] - s;

    unsigned acc = before;
    for (int bin = base + 15; bin >= base; --bin) {
        unsigned hh = h[SWS(bin)];
        if (acc + hh >= PRE_NMS) { atomicMax(&sT, (unsigned)bin); break; }
        acc += hh;
    }
    __syncthreads();
    unsigned T = sT;

    acc = before;
    for (int bin = base + 15; bin >= base; --bin) {
        unsigned hh = h[SWS(bin)];
        if ((unsigned)bin == T) cnt[b] = acc + hh;
        h[SWS(bin)] = acc;
        acc += hh;
    }
    if (t == 0) thresh[b] = T;
    __syncthreads();

    unsigned* r = bbro + (size_t)b * NBS;
    unsigned* m = bbmut + (size_t)b * NBS;
    for (int i = t; i < NBS; i += 1024) {
        unsigned v = h[SWS(i)];
        r[i] = v;
        m[SWB(i)] = v;
    }
}

// K4: bin-segmented scatter — slot allocated by atomicAdd on the SWIZZLED
// mutable binbase copy.
__global__ void k_scatter(
    const unsigned* __restrict__ keys, const unsigned* __restrict__ thresh,
    unsigned* __restrict__ bbmut, unsigned long long* __restrict__ seg)
{
    int gt = blockIdx.x * blockDim.x + threadIdx.x;
    int pix  = gt & (NPIX - 1);
    int rest = gt >> 14;
    int a = rest % A_NUM;
    int b = rest / A_NUM;

    unsigned key = keys[gt];
    unsigned bin = key >> 18;
    if (bin >= thresh[b]) {
        unsigned pos = atomicAdd(&bbmut[(size_t)b * NBS + SWB(bin)], 1u);
        if (pos < SEGL) {
            unsigned idx = (unsigned)(pix * A_NUM + a);
            seg[(size_t)b * SEGL + pos] =
                ((unsigned long long)key << 32) | (unsigned long long)(0xFFFFFFFFu - idx);
        }
    }
}

// K5a: many-block counting rank (32 blocks x 256 thr per batch, all CUs).
__global__ __launch_bounds__(256) void k_rank(
    const unsigned long long* __restrict__ seg, const unsigned* __restrict__ cnt,
    const unsigned* __restrict__ bbro, unsigned* __restrict__ ridx)
{
    int b = blockIdx.x >> 5;
    int p = ((blockIdx.x & 31) << 8) + threadIdx.x;
    unsigned n = cnt[b];
    if (n > SEGL) n = SEGL;
    if (p >= (int)n) return;

    const unsigned long long* S = seg + (size_t)b * SEGL;
    unsigned long long key = S[p];
    unsigned bin = (unsigned)(key >> 50);
    const unsigned* bb = bbro + (size_t)b * NBS;
    unsigned base = bb[bin];
    unsigned end = (bin > 0) ? bb[bin - 1] : n;
    if (end > n) end = n;

    unsigned rank = base;
    unsigned q = base;
    for (; q + 8 <= end; q += 8) {
        unsigned long long v0 = S[q + 0], v1 = S[q + 1];
        unsigned long long v2 = S[q + 2], v3 = S[q + 3];
        unsigned long long v4 = S[q + 4], v5 = S[q + 5];
        unsigned long long v6 = S[q + 6], v7 = S[q + 7];
        rank += (unsigned)(v0 > key) + (unsigned)(v1 > key)
              + (unsigned)(v2 > key) + (unsigned)(v3 > key)
              + (unsigned)(v4 > key) + (unsigned)(v5 > key)
              + (unsigned)(v6 > key) + (unsigned)(v7 > key);
    }
    for (; q < end; ++q) rank += (unsigned)(S[q] > key);

    if (rank < PRE_NMS)
        ridx[(size_t)b * PRE_NMS + rank] = 0xFFFFFFFFu - (unsigned)(key & 0xFFFFFFFFull);
}

// K5b: decode one box per output rank across all CUs.
__global__ void k_decode2(
    const unsigned* __restrict__ ridx,
    const float* __restrict__ deltas, const float* __restrict__ im_info,
    const float* __restrict__ anchors, float* __restrict__ boxes)
{
    int gt = blockIdx.x * blockDim.x + threadIdx.x;
    if (gt >= B_NUM * PRE_NMS) return;
    int b = gt / PRE_NMS;
    int idx = (int)ridx[gt];
    float x1, y1, x2, y2; bool v;
    decode_box(b, idx, deltas, im_info, anchors, x1, y1, x2, y2, v);
    *(float4*)(boxes + (size_t)gt * 4) = make_float4(x1, y1, x2, y2);
}

// One row of a 64x64 suppression block (exact ref op order; div only in the
// proven +-6e-7*uni band — validated absmax=0 since round 6).
__device__ __forceinline__ unsigned long long iou_row(
    float4 bi, float ia, float jx1, float jy1, float jx2, float jy2, float ja)
{
    float xx1 = fmaxf(bi.x, jx1);
    float yy1 = fmaxf(bi.y, jy1);
    float xx2 = fminf(bi.z, jx2);
    float yy2 = fminf(bi.w, jy2);
    float iw = fmaxf(0.0f, __fadd_rn(__fsub_rn(xx2, xx1), 1.0f));
    float ih = fmaxf(0.0f, __fadd_rn(__fsub_rn(yy2, yy1), 1.0f));
    float inter = __fmul_rn(iw, ih);
    float uni = __fsub_rn(__fadd_rn(ia, ja), inter);
    float diff = __fsub_rn(inter, __fmul_rn(NMS_THRESH_F, uni));
    unsigned long long sup = __ballot(diff > 0.0f);
    unsigned long long band = __ballot(fabsf(diff) <= __fmul_rn(6e-7f, uni));
    if (band) {
        unsigned long long supd = __ballot(__fdiv_rn(inter, uni) > NMS_THRESH_F);
        sup = (sup & ~band) | (supd & band);
    }
    return sup;
}

// K6: IoU suppression bitmask for row-tiles R in [Rstart, ...), ngroups
// 8-column groups per batch. statep!=null: skip batch if its scan already
// finished (done flag). Layout mask[b][R][C][64].
__global__ __launch_bounds__(256) void k_iou_mask(
    const float* __restrict__ boxes, unsigned long long* __restrict__ mask,
    int Rstart, int ngroups, const char* __restrict__ statep)
{
    int bid = blockIdx.x;
    int b = bid / ngroups;
    int g = bid - b * ngroups;
    if (statep && ((const int*)(statep + (size_t)b * STATE_STRIDE))[1]) return;

    int R = Rstart;
    while (g >= ((RT_TILES - R + 7) >> 3)) { g -= (RT_TILES - R + 7) >> 3; ++R; }

    int wave = threadIdx.x >> 6;
    int lane = threadIdx.x & 63;
    const float* Bb = boxes + (size_t)b * PRE_NMS * 4;

    __shared__ float4 rb4[64];
    __shared__ float rba[64];
    if (threadIdx.x < 64) {
        int il = R * 64 + threadIdx.x;
        float4 rv = make_float4(0.f, 0.f, -1.f, -1.f);
        if (il < PRE_NMS) rv = *(const float4*)(Bb + 4 * (size_t)il);
        rb4[threadIdx.x] = rv;
        rba[threadIdx.x] = __fmul_rn(__fadd_rn(__fsub_rn(rv.z, rv.x), 1.0f),
                                     __fadd_rn(__fsub_rn(rv.w, rv.y), 1.0f));
    }
    __syncthreads();

    int C1 = R + g * 8 + wave * 2;
    int C2 = C1 + 1;
    if (C1 >= RT_TILES) return;   // tail waves idle (no barriers below)

    float j1x1 = 0.f, j1y1 = 0.f, j1x2 = -1.f, j1y2 = -1.f;
    float j2x1 = 0.f, j2y1 = 0.f, j2x2 = -1.f, j2y2 = -1.f;
    int j1 = C1 * 64 + lane;
    int j2 = C2 * 64 + lane;
    if (j1 < PRE_NMS) {
        float4 v = *(const float4*)(Bb + 4 * (size_t)j1);
        j1x1 = v.x; j1y1 = v.y; j1x2 = v.z; j1y2 = v.w;
    }
    if (C2 < RT_TILES && j2 < PRE_NMS) {
        float4 v = *(const float4*)(Bb + 4 * (size_t)j2);
        j2x1 = v.x; j2y1 = v.y; j2x2 = v.z; j2y2 = v.w;
    }
    float j1a = __fmul_rn(__fadd_rn(__fsub_rn(j1x2, j1x1), 1.0f),
                          __fadd_rn(__fsub_rn(j1y2, j1y1), 1.0f));
    float j2a = __fmul_rn(__fadd_rn(__fsub_rn(j2x2, j2x1), 1.0f),
                          __fadd_rn(__fsub_rn(j2y2, j2y1), 1.0f));

    unsigned long long w1 = 0ULL, w2 = 0ULL;
    if (C1 == R) {   // diagonal tile
        #pragma unroll 4
        for (int ri = 0; ri < 64; ++ri) {
            float4 bi = rb4[ri];
            float ia = rba[ri];
            unsigned long long s1 = iou_row(bi, ia, j1x1, j1y1, j1x2, j1y2, j1a)
                                    & (0xFFFFFFFFFFFFFFFEull << ri);
            unsigned long long s2 = iou_row(bi, ia, j2x1, j2y1, j2x2, j2y2, j2a);
            w1 = (lane == ri) ? s1 : w1;
            w2 = (lane == ri) ? s2 : w2;
        }
    } else {
        #pragma unroll 4
        for (int ri = 0; ri < 64; ++ri) {
            float4 bi = rb4[ri];
            float ia = rba[ri];
            unsigned long long s1 = iou_row(bi, ia, j1x1, j1y1, j1x2, j1y2, j1a);
            unsigned long long s2 = iou_row(bi, ia, j2x1, j2y1, j2x2, j2y2, j2a);
            w1 = (lane == ri) ? s1 : w1;
            w2 = (lane == ri) ? s2 : w2;
        }
    }

    unsigned long long* Mb = mask + (size_t)b * BQWORDS;
    Mb[(size_t)(R * RT_TILES + C1) * 64 + lane] = w1;
    if (C2 < RT_TILES)
        Mb[(size_t)(R * RT_TILES + C2) * 64 + lane] = w2;
}

// K6b: transpose head mask [R][C][64] -> row-major tmask[i][C] for rows
// < ROWS_SPLIT; also emit diagw[i] = tmask[i][i>>6].
__global__ __launch_bounds__(1024) void k_transpose(
    const unsigned long long* __restrict__ mask,
    unsigned long long* __restrict__ tmask,
    unsigned long long* __restrict__ diagw)
{
    __shared__ unsigned long long tile[64 * RT_TILES];   // 48,128 B
    int b = blockIdx.x >> 4;
    int R = blockIdx.x & 15;
    int t = threadIdx.x;
    const unsigned long long* Mb =
        mask + (size_t)b * BQWORDS + (size_t)R * RT_TILES * 64;
    for (int idx = t; idx < RT_TILES * 64; idx += 1024) {
        int C = idx >> 6, r = idx & 63;
        tile[r * RT_TILES + C] = Mb[(size_t)C * 64 + r];
    }
    __syncthreads();
    unsigned long long* Tb =
        tmask + (size_t)b * TMQ + (size_t)R * 64 * RT_TILES;
    for (int idx = t; idx < 64 * RT_TILES; idx += 1024)
        Tb[idx] = tile[idx];
    if (t < 64)
        diagw[(size_t)b * ROWS_SPLIT + R * 64 + t] = tile[t * RT_TILES + R];
}

// K7: greedy scan, resumable. One wave/batch. Suppression state in
// registers (lane l owns words l, 64+l).
// p1 (final_phase==0): branchless row-major scan, round-30 issue-count
// cuts: (1) unconditional klist store (garbage at klist[kept] from
// non-kept rows is overwritten by the next kept row before kept advances;
// slots >= final kept never read); (2) per-row kept<POST clamp removed —
// kept may run past 300 within a 16-row group (greedy decisions stay
// correct since suppression ORs continue; overflow entries land in
// klist[300..315], never read), clamped after the loop; (3) row-index
// clamp removed from the prefetch (overrun reads 12KB of dead phist
// region — in-bounds, never consumed).
// p2 (final_phase==1): old per-row path on the strided mask layout.
__global__ __launch_bounds__(64) void k_nms_scan_part(
    const unsigned long long* __restrict__ mask,
    const unsigned long long* __restrict__ tmask,
    const unsigned long long* __restrict__ diagw,
    const float* __restrict__ boxes, float* __restrict__ out,
    char* __restrict__ statep, int row_begin, int row_end, int final_phase)
{
    const int b = blockIdx.x;
    const int l = threadIdx.x;
    char* st = statep + (size_t)b * STATE_STRIDE;
    int* s_meta = (int*)st;
    unsigned long long* s_supp = (unsigned long long*)(st + 16);
    int* s_klist = (int*)(st + 768);

    __shared__ int klist[POST_NMS + 16];
    unsigned long long reg0, reg1;   // suppression words l and 64+l
    int kept, done;

    if (row_begin == 0) {
        reg0 = 0ULL; reg1 = 0ULL;
        kept = 0; done = 0;
    } else {
        kept = s_meta[0];
        done = s_meta[1];
        reg0 = s_supp[l];
        reg1 = (l < RT_TILES - 64) ? s_supp[64 + l] : 0ULL;
        for (int k = l; k < POST_NMS; k += 64) klist[k] = s_klist[k];
    }
    __syncthreads();

    const unsigned long long* __restrict__ M = mask + (size_t)b * BQWORDS;
    const unsigned long long* __restrict__ TM = tmask + (size_t)b * TMQ;
    const unsigned long long* __restrict__ DW = diagw + (size_t)b * ROWS_SPLIT;
    unsigned long long curw = 0; int curwi = -1;

#define LOADROW_T(p0, p1, dwv, i) { \
        const unsigned long long* _r = TM + (size_t)(i) * RT_TILES; \
        p0 = _r[l]; \
        p1 = (l < RT_TILES - 64) ? _r[64 + l] : 0ULL; \
        dwv = DW[i]; }

#define LOADROW(p0, p1, i) { \
        int _i = ((i) < PRE_NMS) ? (i) : (PRE_NMS - 1); \
        int _R = _i >> 6; \
        const unsigned long long* _r = M + (size_t)(_R * RT_TILES) * 64 + (_i & 63); \
        p0 = 0ULL; p1 = 0ULL; \
        if (l >= _R) p0 = _r[l * 64]; \
        if (l < RT_TILES - 64 && 64 + l >= _R) p1 = _r[(64 + l) * 64]; }

#define STEP(i, p0, p1) { \
        if (kept < POST_NMS) { \
            int _wi = (i) >> 6; \
            if (_wi != curwi) { \
                curw = (_wi < 64) ? __shfl(reg0, _wi) : __shfl(reg1, _wi - 64); \
                curwi = _wi; \
            } \
            if (!((curw >> ((i) & 63)) & 1ULL)) { \
                if (l == 0) klist[kept] = (i); \
                unsigned long long _d = (_wi < 64) ? __shfl(p0, _wi) \
                                                   : __shfl(p1, _wi - 64); \
                reg0 |= p0; \
                reg1 |= p1; \
                curw |= _d; \
                ++kept; \
            } \
        } }

    if (!done && kept < POST_NMS) {
        if (!final_phase) {
            unsigned long long p[16][2], dw[16];
            #pragma unroll
            for (int k = 0; k < 16; ++k) { LOADROW_T(p[k][0], p[k][1], dw[k], row_begin + k) }
            for (int i = row_begin; i < row_end && kept < POST_NMS; i += 16) {
                // groups of 16 never straddle a 64-row tile: hoist seed
                int wi = i >> 6;
                if (wi != curwi) { curw = __shfl(reg0, wi); curwi = wi; }
                int ib = i & 63;
                #pragma unroll
                for (int k = 0; k < 16; ++k) {
                    // branchless step (no per-row kept clamp)
                    int keep = (int)((~(curw >> (ib + k))) & 1ULL);
                    unsigned long long m = 0ULL - (unsigned long long)keep;
                    if (l == 0) klist[kept] = i + k;
                    reg0 |= p[k][0] & m;
                    reg1 |= p[k][1] & m;
                    curw |= dw[k] & m;
                    kept += keep;
                    LOADROW_T(p[k][0], p[k][1], dw[k], i + 16 + k)
                }
            }
            if (kept > POST_NMS) kept = POST_NMS;
        } else {
            unsigned long long p[16][2];
            #pragma unroll
            for (int k = 0; k < 16; ++k) { LOADROW(p[k][0], p[k][1], row_begin + k) }
            for (int i = row_begin; i < row_end && kept < POST_NMS; i += 16) {
                #pragma unroll
                for (int k = 0; k < 16; ++k) {
                    STEP(i + k, p[k][0], p[k][1])
                    LOADROW(p[k][0], p[k][1], i + 16 + k)
                }
            }
        }
    }
    __syncthreads();

    if (!final_phase) {
        if (l == 0) { s_meta[0] = kept; s_meta[1] = (kept >= POST_NMS) ? 1 : 0; }
        s_supp[l] = reg0;
        if (l < RT_TILES - 64) s_supp[64 + l] = reg1;
        for (int k = l; k < POST_NMS; k += 64) s_klist[k] = klist[k];
    } else {
        for (int k = l; k < POST_NMS; k += 64) {
            size_t o = ((size_t)b * POST_NMS + k) * 5;
            float x1 = 0.f, y1 = 0.f, x2 = 0.f, y2 = 0.f;
            if (k < kept) {
                int idx = klist[k];
                const float4 v = *(const float4*)(boxes + ((size_t)b * PRE_NMS + idx) * 4);
                x1 = v.x; y1 = v.y; x2 = v.z; y2 = v.w;
            }
            out[o + 0] = (float)b;
            out[o + 1] = x1; out[o + 2] = y1; out[o + 3] = x2; out[o + 4] = y2;
        }
    }
#undef LOADROW_T
#undef LOADROW
#undef STEP
}

// Fallback NMS (used only if ws_size is too small for the bitmask).
__global__ __launch_bounds__(1024) void k_nms_out(
    const float* __restrict__ boxes, float* __restrict__ out)
{
    __shared__ float bx1[PRE_NMS], by1[PRE_NMS], bx2[PRE_NMS], by2[PRE_NMS], bar[PRE_NMS];
    __shared__ unsigned rem[(PRE_NMS + 31) / 32];
    __shared__ int kept_idx[POST_NMS];

    int b = blockIdx.x;
    int t = threadIdx.x;

    for (int p = t; p < PRE_NMS; p += 1024) {
        size_t o = ((size_t)b * PRE_NMS + p) * 4;
        float x1 = boxes[o], y1 = boxes[o + 1], x2 = boxes[o + 2], y2 = boxes[o + 3];
        bx1[p] = x1; by1[p] = y1; bx2[p] = x2; by2[p] = y2;
        bar[p] = __fmul_rn(__fadd_rn(__fsub_rn(x2, x1), 1.0f),
                           __fadd_rn(__fsub_rn(y2, y1), 1.0f));
    }
    for (int p = t; p < (PRE_NMS + 31) / 32; p += 1024) rem[p] = 0u;
    __syncthreads();

    int kept = 0;
    for (int i = 0; i < PRE_NMS && kept < POST_NMS; ++i) {
        if (rem[i >> 5] & (1u << (i & 31))) continue;
        if (t == 0) kept_idx[kept] = i;
        float xi1 = bx1[i], yi1 = by1[i], xi2 = bx2[i], yi2 = by2[i], ai = bar[i];
        for (int j = i + 1 + t; j < PRE_NMS; j += 1024) {
            float xx1 = fmaxf(xi1, bx1[j]);
            float yy1 = fmaxf(yi1, by1[j]);
            float xx2 = fminf(xi2, bx2[j]);
            float yy2 = fminf(yi2, by2[j]);
            float iw = fmaxf(0.0f, __fadd_rn(__fsub_rn(xx2, xx1), 1.0f));
            float ih = fmaxf(0.0f, __fadd_rn(__fsub_rn(yy2, yy1), 1.0f));
            float inter = __fmul_rn(iw, ih);
            if (inter > 0.0f) {
                float uni = __fsub_rn(__fadd_rn(ai, bar[j]), inter);
                float iou = __fdiv_rn(inter, uni);
                if (iou > NMS_THRESH_F) atomicOr(&rem[j >> 5], 1u << (j & 31));
            }
        }
        ++kept;
        __syncthreads();
    }

    for (int k = t; k < POST_NMS; k += 1024) {
        size_t o = ((size_t)b * POST_NMS + k) * 5;
        out[o] = (float)b;
        if (k < kept) {
            int ii = kept_idx[k];
            out[o + 1] = bx1[ii]; out[o + 2] = by1[ii];
            out[o + 3] = bx2[ii]; out[o + 4] = by2[ii];
        } else {
            out[o + 1] = 0.0f; out[o + 2] = 0.0f; out[o + 3] = 0.0f; out[o + 4] = 0.0f;
        }
    }
}

extern "C" void kernel_launch(void* const* d_in, const int* in_sizes, int n_in,
                              void* d_out, int out_size, void* d_ws, size_t ws_size,
                              hipStream_t stream)
{
    const float* scores  = (const float*)d_in[0];
    const float* deltas  = (const float*)d_in[1];
    const float* im_info = (const float*)d_in[2];
    const float* anchors = (const float*)d_in[3];
    float* out = (float*)d_out;
    char* ws = (char*)d_ws;

    unsigned* keys             = (unsigned*)(ws + OFF_KEYS);
    unsigned* phist            = (unsigned*)(ws + OFF_PHIST);
    unsigned long long* tmask  = (unsigned long long*)(ws + OFF_TMASK);
    float* boxes               = (float*)(ws + OFF_BOXES);
    unsigned* bbro             = (unsigned*)(ws + OFF_BBRO);
    unsigned* bbmut            = (unsigned*)(ws + OFF_BBMUT);
    unsigned* thresh           = (unsigned*)(ws + OFF_CNT);
    unsigned* cnt              = thresh + 8;
    unsigned long long* seg    = (unsigned long long*)(ws + OFF_SEG);
    unsigned* ridx             = (unsigned*)(ws + OFF_RIDX);
    char* state                = (char*)(ws + OFF_STATE);
    unsigned long long* diagw  = (unsigned long long*)(ws + OFF_DIAG);
    unsigned long long* mask   = (unsigned long long*)(ws + OFF_MASK);

    int total = B_NUM * N_ANCH;
    int blk = 256;
    k_decode<<<(total + blk - 1) / blk, blk, 0, stream>>>(
        scores, deltas, im_info, anchors, keys);
    k_hist_part<<<B_NUM * 4, 1024, 0, stream>>>(keys, phist);
    k_thresh2<<<B_NUM, 1024, 0, stream>>>(phist, bbro, bbmut, thresh, cnt);
    k_scatter<<<(total + blk - 1) / blk, blk, 0, stream>>>(
        keys, thresh, bbmut, seg);
    k_rank<<<B_NUM * 32, 256, 0, stream>>>(seg, cnt, bbro, ridx);
    k_decode2<<<(B_NUM * PRE_NMS + blk - 1) / blk, blk, 0, stream>>>(
        ridx, deltas, im_info, anchors, boxes);

    if (ws_size >= (size_t)OFF_MASK + MASK_BYTES) {
        // phase A: rows 0..1023 only
        k_iou_mask<<<B_NUM * G_HEAD, 256, 0, stream>>>(
            boxes, mask, 0, G_HEAD, (const char*)0);
        // transpose head rows to row-major + extract diagonal words
        k_transpose<<<B_NUM * R_SPLIT, 1024, 0, stream>>>(mask, tmask, diagw);
        // scan p1: row-major scan, branchless + trimmed issue count
        k_nms_scan_part<<<B_NUM, 64, 0, stream>>>(
            mask, tmask, diagw, boxes, out, state, 0, ROWS_SPLIT, 0);
        // tail: rows >= 1024, skipped per batch when done
        k_iou_mask<<<B_NUM * G_TAIL, 256, 0, stream>>>(
            boxes, mask, R_SPLIT, G_TAIL, (const char*)state);
        // scan p2: finish (or just write output if already done)
        k_nms_scan_part<<<B_NUM, 64, 0, stream>>>(
            mask, tmask, diagw, boxes, out, state, ROWS_SPLIT, PRE_NMS, 1);
    } else {
        k_nms_out<<<B_NUM, 1024, 0, stream>>>(boxes, out);
    }
}